// Round 11
// baseline (578.308 us; speedup 1.0000x reference)
//
#include <hip/hip_runtime.h>
#include <math.h>

// Problem constants (from reference): N=100000, E=1600000, D_IN=D_H=128, D_OUT=47
#define DH 128
#define DOUT 47
#define BN_EPS 1e-5f

typedef __attribute__((ext_vector_type(8))) short short8;
typedef __attribute__((ext_vector_type(4))) float float4v;

// ---------------------------------------------------------------------------
// bf16 pack/unpack (RNE).
// ---------------------------------------------------------------------------
__device__ __forceinline__ unsigned bf16_rne(float f) {
    unsigned u = __float_as_uint(f);
    return (u + 0x7fffu + ((u >> 16) & 1u)) >> 16;
}
__device__ __forceinline__ unsigned pack_bf2(float a, float b) {
    return (bf16_rne(a) & 0xffffu) | (bf16_rne(b) << 16);
}
__device__ __forceinline__ float2 unpack_bf2(unsigned u) {
    return make_float2(__uint_as_float(u << 16),
                       __uint_as_float(u & 0xffff0000u));
}

// ---------------------------------------------------------------------------
// CSR build helpers. Edge lists PADDED to multiple of 8 records per node.
// ---------------------------------------------------------------------------

__global__ void zero_int_k(int* __restrict__ p, int n) {
    int i = blockIdx.x * 256 + threadIdx.x;
    if (i < n) p[i] = 0;
}

// count: 4 consecutive edges per thread (int4 load), fire-and-forget atomics.
__global__ __launch_bounds__(256) void count4_k(const int* __restrict__ dst,
                                                int* __restrict__ counts,
                                                int e, int n) {
    int i0 = (blockIdx.x * 256 + threadIdx.x) * 4;
    if (i0 + 4 <= e) {
        int4 d4 = *(const int4*)(dst + i0);
        atomicAdd(&counts[d4.x], 1);
        atomicAdd(&counts[d4.y], 1);
        atomicAdd(&counts[d4.z], 1);
        atomicAdd(&counts[d4.w], 1);
    } else {
        for (int i = i0; i < e; i++) atomicAdd(&counts[dst[i]], 1);
    }
}

// scan1 scans PADDED counts ((c+7)&~7).
__global__ __launch_bounds__(256) void scan1_k(const int* __restrict__ counts,
                                               int* __restrict__ offsets,
                                               int* __restrict__ blocksums, int n) {
    __shared__ int sd[256];
    int tid = threadIdx.x;
    int base = blockIdx.x * 1024 + tid * 4;
    int v0 = (base + 0 < n) ? ((counts[base + 0] + 7) & ~7) : 0;
    int v1 = (base + 1 < n) ? ((counts[base + 1] + 7) & ~7) : 0;
    int v2 = (base + 2 < n) ? ((counts[base + 2] + 7) & ~7) : 0;
    int v3 = (base + 3 < n) ? ((counts[base + 3] + 7) & ~7) : 0;
    int tsum = v0 + v1 + v2 + v3;
    sd[tid] = tsum;
    __syncthreads();
    for (int off = 1; off < 256; off <<= 1) {
        int x = (tid >= off) ? sd[tid - off] : 0;
        __syncthreads();
        sd[tid] += x;
        __syncthreads();
    }
    if (tid == 255) blocksums[blockIdx.x] = sd[255];
    int run = sd[tid] - tsum;
    if (base + 0 < n) offsets[base + 0] = run;  run += v0;
    if (base + 1 < n) offsets[base + 1] = run;  run += v1;
    if (base + 2 < n) offsets[base + 2] = run;  run += v2;
    if (base + 3 < n) offsets[base + 3] = run;
}

__global__ __launch_bounds__(128) void scan2_k(int* __restrict__ blocksums, int nb) {
    __shared__ int sd[128];
    int tid = threadIdx.x;
    int v = (tid < nb) ? blocksums[tid] : 0;
    sd[tid] = v;
    __syncthreads();
    for (int off = 1; off < 128; off <<= 1) {
        int x = (tid >= off) ? sd[tid - off] : 0;
        __syncthreads();
        sd[tid] += x;
        __syncthreads();
    }
    if (tid < nb) blocksums[tid] = sd[tid] - v;  // exclusive
}

// finalize: padded offsets, cursor, dinv, and writes the pad records.
__global__ void finalize_k(int* __restrict__ offsets, int* __restrict__ cursor,
                           float* __restrict__ dinv, const int* __restrict__ counts,
                           const int* __restrict__ blocksums,
                           int2* __restrict__ ew, int n) {
    int i = blockIdx.x * 256 + threadIdx.x;
    if (i >= n) return;
    int o = offsets[i] + blocksums[i >> 10];
    offsets[i] = o;
    cursor[i] = o;
    int c = counts[i];
    dinv[i] = rsqrtf((float)(c + 1));  // +1 self-loop; deg>=1 always
    int cP = (c + 7) & ~7;
    int2 z; z.x = 0; z.y = 0;
    for (int j = o + c; j < o + cP; ++j) ew[j] = z;  // pad: row 0, weight 0
}

// ---------------------------------------------------------------------------
// fill: standalone (0 LDS, 8 VGPR -> full occupancy; R10's fusion into the
// 34KB-LDS gemm kernel capped residency and serialized). 4 consecutive edges
// per thread; 4 independent atomic round-trips in flight.
// ---------------------------------------------------------------------------
__global__ __launch_bounds__(256) void fill4_k(const int* __restrict__ src,
                                               const int* __restrict__ dst,
                                               const float* __restrict__ dinv,
                                               int* __restrict__ cursor,
                                               int2* __restrict__ ew, int e) {
    int i0 = (blockIdx.x * 256 + threadIdx.x) * 4;
    if (i0 + 4 <= e) {
        int4 s4 = *(const int4*)(src + i0);
        int4 d4 = *(const int4*)(dst + i0);
        int sa[4] = {s4.x, s4.y, s4.z, s4.w};
        int da[4] = {d4.x, d4.y, d4.z, d4.w};
        float w[4];
#pragma unroll
        for (int k = 0; k < 4; k++) w[k] = dinv[sa[k]] * dinv[da[k]];
        int p[4];
#pragma unroll
        for (int k = 0; k < 4; k++) p[k] = atomicAdd(&cursor[da[k]], 1);
#pragma unroll
        for (int k = 0; k < 4; k++) {
            int2 r; r.x = sa[k]; r.y = __float_as_int(w[k]);
            ew[p[k]] = r;
        }
    } else {
        for (int i = i0; i < e; i++) {
            int s = src[i], d = dst[i];
            int pos = atomicAdd(&cursor[d], 1);
            int2 r; r.x = s; r.y = __float_as_int(dinv[s] * dinv[d]);
            ew[pos] = r;
        }
    }
}

// ---------------------------------------------------------------------------
// Weight prep: W fp32 [k][n] -> bf16 transposed [n][k] (64 uints/row).
// ---------------------------------------------------------------------------
__global__ __launch_bounds__(256) void wprep_k(const float* __restrict__ W1,
                                               const float* __restrict__ W2,
                                               unsigned* __restrict__ W1b,
                                               unsigned* __restrict__ W2b) {
    const float* W = blockIdx.x ? W2 : W1;
    unsigned* Wb = blockIdx.x ? W2b : W1b;
    int tid = threadIdx.x;
    for (int p = tid; p < 128 * 32; p += 256) {
        int n = p >> 5;
        int k0 = (p & 31) << 2;
        float f0 = W[(size_t)(k0 + 0) * 128 + n];
        float f1 = W[(size_t)(k0 + 1) * 128 + n];
        float f2 = W[(size_t)(k0 + 2) * 128 + n];
        float f3 = W[(size_t)(k0 + 3) * 128 + n];
        uint2 v;
        v.x = pack_bf2(f0, f1);
        v.y = pack_bf2(f2, f3);
        *(uint2*)(Wb + (size_t)n * 64 + (k0 >> 1)) = v;
    }
}

// ---------------------------------------------------------------------------
// MFMA GEMM: C[M x 128] = A[M x 128] @ W[128 x 128], A fp32 split hi/lo bf16
// in-register, W bf16 [n][k] staged in LDS. Output packed bf16 table.
// ---------------------------------------------------------------------------
__global__ __launch_bounds__(256) void gemm_mfma_k(const float* __restrict__ A,
                                                   const unsigned* __restrict__ Wb,
                                                   unsigned* __restrict__ Cb, int M) {
    __shared__ ushort Bl[128 * 136];
    int tid = threadIdx.x;
    {
        unsigned* Bu = (unsigned*)Bl;
        for (int q = tid; q < 128 * 16; q += 256) {
            int row = q >> 4;
            int c = (q & 15) << 2;
            uint4 v = *(const uint4*)(Wb + (size_t)row * 64 + c);
            *(uint4*)(Bu + (size_t)row * 68 + c) = v;
        }
    }
    __syncthreads();

    int lane = tid & 63;
    int wv = tid >> 6;
    int quad = lane >> 4;
    int l15 = lane & 15;
    int r0 = blockIdx.x * 64 + wv * 16;
    int mload = r0 + l15;
    if (mload > M - 1) mload = M - 1;
    const float* Ar = A + (size_t)mload * 128 + quad * 8;

    float4v acc[8];
#pragma unroll
    for (int t = 0; t < 8; t++) acc[t] = (float4v){0.f, 0.f, 0.f, 0.f};

    for (int kp = 0; kp < 4; ++kp) {
        float4 a0 = *(const float4*)(Ar + kp * 32);
        float4 a1 = *(const float4*)(Ar + kp * 32 + 4);
        float af[8] = {a0.x, a0.y, a0.z, a0.w, a1.x, a1.y, a1.z, a1.w};
        short8 hi, lo;
#pragma unroll
        for (int j = 0; j < 8; j++) {
            unsigned h = bf16_rne(af[j]);
            hi[j] = (short)h;
            float res = af[j] - __uint_as_float(h << 16);
            lo[j] = (short)bf16_rne(res);
        }
        int kb = kp * 32 + quad * 8;
#pragma unroll
        for (int nt = 0; nt < 8; nt++) {
            short8 b8 = *(const short8*)(&Bl[(size_t)(nt * 16 + l15) * 136 + kb]);
            acc[nt] = __builtin_amdgcn_mfma_f32_16x16x32_bf16(hi, b8, acc[nt], 0, 0, 0);
            acc[nt] = __builtin_amdgcn_mfma_f32_16x16x32_bf16(lo, b8, acc[nt], 0, 0, 0);
        }
    }

    ushort* Cu = (ushort*)Cb;
#pragma unroll
    for (int r = 0; r < 4; r++) {
        int row = r0 + quad * 4 + r;
        if (row < M) {
#pragma unroll
            for (int nt = 0; nt < 8; nt++) {
                Cu[(size_t)row * 128 + nt * 16 + l15] = (ushort)bf16_rne(acc[nt][r]);
            }
        }
    }
}

// ---------------------------------------------------------------------------
// Aggregation core: one wave per node. Half-wave h handles edges 2k+h of each
// 8-edge group; lane loads uint2 (4 bf16 feats). Padded CSR -> no masking.
// ---------------------------------------------------------------------------
__device__ __forceinline__ float4 agg_core(const uint2* __restrict__ Hu2,
                                           const int2* __restrict__ ew,
                                           int start, int cnt, int node,
                                           int li, int half, float di) {
    float4 acc = make_float4(0.f, 0.f, 0.f, 0.f);
    int groups = ((cnt + 7) & ~7) >> 3;
    if (groups > 0) {
        const int2* p = ew + start + half;
        int2 r[4];
#pragma unroll
        for (int k = 0; k < 4; k++) r[k] = p[2 * k];
        for (int g = 0; g < groups; ++g) {
            uint2 gb[4];
#pragma unroll
            for (int k = 0; k < 4; k++)
                gb[k] = Hu2[(size_t)r[k].x * 32 + li];
            int2 rn[4];
            const int2* pn = p + 8 * (g + 1);
#pragma unroll
            for (int k = 0; k < 4; k++) rn[k] = pn[2 * k];
#pragma unroll
            for (int k = 0; k < 4; k++) {
                float w = __int_as_float(r[k].y);
                float2 f0 = unpack_bf2(gb[k].x);
                float2 f1 = unpack_bf2(gb[k].y);
                acc.x = fmaf(f0.x, w, acc.x);
                acc.y = fmaf(f0.y, w, acc.y);
                acc.z = fmaf(f1.x, w, acc.z);
                acc.w = fmaf(f1.y, w, acc.w);
            }
#pragma unroll
            for (int k = 0; k < 4; k++) r[k] = rn[k];
        }
    }
    acc.x += __shfl_xor(acc.x, 32);
    acc.y += __shfl_xor(acc.y, 32);
    acc.z += __shfl_xor(acc.z, 32);
    acc.w += __shfl_xor(acc.w, 32);
    uint2 sv = Hu2[(size_t)node * 32 + li];
    float ws = di * di;
    float2 s0 = unpack_bf2(sv.x);
    float2 s1 = unpack_bf2(sv.y);
    acc.x = fmaf(s0.x, ws, acc.x);
    acc.y = fmaf(s0.y, ws, acc.y);
    acc.z = fmaf(s1.x, ws, acc.z);
    acc.w = fmaf(s1.y, ws, acc.w);
    return acc;
}

// Layer 1: + b1, BN(eval), ReLU -> H1 (fp32)
__global__ __launch_bounds__(256) void agg1_k(
    const unsigned* __restrict__ H, const int2* __restrict__ ew,
    const int* __restrict__ offsets, const int* __restrict__ counts,
    const float* __restrict__ dinv, const float* __restrict__ b1,
    const float* __restrict__ gamma, const float* __restrict__ beta,
    const float* __restrict__ mean, const float* __restrict__ var,
    float* __restrict__ H1, int n) {
    int lane = threadIdx.x & 63;
    int li = lane & 31;
    int half = lane >> 5;
    int node = blockIdx.x * 4 + (threadIdx.x >> 6);
    if (node >= n) return;
    float4 acc = agg_core((const uint2*)H, ew, offsets[node], counts[node],
                          node, li, half, dinv[node]);
    if (half == 0) {
        int f0 = li * 4;
        float4 bb = *(const float4*)(b1 + f0);
        float4 mm = *(const float4*)(mean + f0);
        float4 vv = *(const float4*)(var + f0);
        float4 gg = *(const float4*)(gamma + f0);
        float4 be = *(const float4*)(beta + f0);
        float4 o;
        o.x = fmaxf((acc.x + bb.x - mm.x) * rsqrtf(vv.x + BN_EPS) * gg.x + be.x, 0.f);
        o.y = fmaxf((acc.y + bb.y - mm.y) * rsqrtf(vv.y + BN_EPS) * gg.y + be.y, 0.f);
        o.z = fmaxf((acc.z + bb.z - mm.z) * rsqrtf(vv.z + BN_EPS) * gg.z + be.z, 0.f);
        o.w = fmaxf((acc.w + bb.w - mm.w) * rsqrtf(vv.w + BN_EPS) * gg.w + be.w, 0.f);
        *(float4*)(H1 + (size_t)node * 128 + f0) = o;
    }
}

// Layer 2: + b2, then JK max with H1 (in-place H1 -> JK)
__global__ __launch_bounds__(256) void agg2_k(
    const unsigned* __restrict__ H, const int2* __restrict__ ew,
    const int* __restrict__ offsets, const int* __restrict__ counts,
    const float* __restrict__ dinv, const float* __restrict__ b2,
    float* __restrict__ H1JK, int n) {
    int lane = threadIdx.x & 63;
    int li = lane & 31;
    int half = lane >> 5;
    int node = blockIdx.x * 4 + (threadIdx.x >> 6);
    if (node >= n) return;
    float4 acc = agg_core((const uint2*)H, ew, offsets[node], counts[node],
                          node, li, half, dinv[node]);
    if (half == 0) {
        int f0 = li * 4;
        float4 bb = *(const float4*)(b2 + f0);
        float4* p = (float4*)(H1JK + (size_t)node * 128 + f0);
        float4 h1v = *p;
        float4 o;
        o.x = fmaxf(h1v.x, acc.x + bb.x);
        o.y = fmaxf(h1v.y, acc.y + bb.y);
        o.z = fmaxf(h1v.z, acc.z + bb.z);
        o.w = fmaxf(h1v.w, acc.w + bb.w);
        *p = o;
    }
}

// ---------------------------------------------------------------------------
// Head: tiled GEMM (64 nodes x 48 cols, K=128) + fused log_softmax.
// ---------------------------------------------------------------------------
__global__ __launch_bounds__(256) void head_k(const float* __restrict__ JK,
                                              const float* __restrict__ Wf,
                                              const float* __restrict__ bf,
                                              float* __restrict__ out, int n) {
    __shared__ __align__(16) float Bs[48 * 132];  // [col][k], stride 132
    __shared__ __align__(16) float As[64 * 36];   // [row][k-in-panel], stride 36
    int tid = threadIdx.x;
    for (int p = tid; p < 47 * 32; p += 256) {
        int c = p >> 5;          // 0..46
        int k0 = (p & 31) << 2;  // 0,4,...,124
        float4 v;
        v.x = Wf[(size_t)(k0 + 0) * DOUT + c];
        v.y = Wf[(size_t)(k0 + 1) * DOUT + c];
        v.z = Wf[(size_t)(k0 + 2) * DOUT + c];
        v.w = Wf[(size_t)(k0 + 3) * DOUT + c];
        *(float4*)(&Bs[c * 132 + k0]) = v;
    }
    int tx = tid & 15;   // col group: cols [3*tx, 3*tx+3)
    int ty = tid >> 4;   // row group: rows [4*ty, 4*ty+4)
    int node0 = blockIdx.x * 64;

    float acc[4][3];
#pragma unroll
    for (int i = 0; i < 4; i++)
#pragma unroll
        for (int j = 0; j < 3; j++) acc[i][j] = 0.f;

    for (int kk = 0; kk < 128; kk += 32) {
        __syncthreads();
        for (int l = tid; l < 512; l += 256) {
            int r = l >> 3;
            int c4 = (l & 7) << 2;
            int row = node0 + r;
            float4 v = make_float4(0.f, 0.f, 0.f, 0.f);
            if (row < n) v = *(const float4*)(JK + (size_t)row * 128 + kk + c4);
            *(float4*)(&As[r * 36 + c4]) = v;
        }
        __syncthreads();
#pragma unroll
        for (int k4 = 0; k4 < 32; k4 += 4) {
            float4 a0 = *(const float4*)(&As[(ty * 4 + 0) * 36 + k4]);
            float4 a1 = *(const float4*)(&As[(ty * 4 + 1) * 36 + k4]);
            float4 a2 = *(const float4*)(&As[(ty * 4 + 2) * 36 + k4]);
            float4 a3 = *(const float4*)(&As[(ty * 4 + 3) * 36 + k4]);
            float4 b0 = *(const float4*)(&Bs[(tx * 3 + 0) * 132 + kk + k4]);
            float4 b1 = *(const float4*)(&Bs[(tx * 3 + 1) * 132 + kk + k4]);
            float4 b2 = *(const float4*)(&Bs[(tx * 3 + 2) * 132 + kk + k4]);
#define DOT_ROW(i, a)                                                        \
            acc[i][0] = fmaf(a.x, b0.x, acc[i][0]);                          \
            acc[i][0] = fmaf(a.y, b0.y, acc[i][0]);                          \
            acc[i][0] = fmaf(a.z, b0.z, acc[i][0]);                          \
            acc[i][0] = fmaf(a.w, b0.w, acc[i][0]);                          \
            acc[i][1] = fmaf(a.x, b1.x, acc[i][1]);                          \
            acc[i][1] = fmaf(a.y, b1.y, acc[i][1]);                          \
            acc[i][1] = fmaf(a.z, b1.z, acc[i][1]);                          \
            acc[i][1] = fmaf(a.w, b1.w, acc[i][1]);                          \
            acc[i][2] = fmaf(a.x, b2.x, acc[i][2]);                          \
            acc[i][2] = fmaf(a.y, b2.y, acc[i][2]);                          \
            acc[i][2] = fmaf(a.z, b2.z, acc[i][2]);                          \
            acc[i][2] = fmaf(a.w, b2.w, acc[i][2]);
            DOT_ROW(0, a0)
            DOT_ROW(1, a1)
            DOT_ROW(2, a2)
            DOT_ROW(3, a3)
#undef DOT_ROW
        }
    }

    float bfv[3];
#pragma unroll
    for (int j = 0; j < 3; j++) {
        int c = tx * 3 + j;
        bfv[j] = (c < DOUT) ? bf[c] : 0.f;
    }
#pragma unroll
    for (int i = 0; i < 4; i++) {
        int node = node0 + ty * 4 + i;
        float l0 = acc[i][0] + bfv[0];
        float l1 = acc[i][1] + bfv[1];
        float l2 = acc[i][2] + bfv[2];
        bool v2ok = (tx * 3 + 2) < DOUT;  // only col 47 (tx=15,j=2) invalid
        float m = fmaxf(l0, l1);
        if (v2ok) m = fmaxf(m, l2);
        for (int off = 8; off >= 1; off >>= 1) m = fmaxf(m, __shfl_xor(m, off));
        float s = expf(l0 - m) + expf(l1 - m) + (v2ok ? expf(l2 - m) : 0.f);
        for (int off = 8; off >= 1; off >>= 1) s += __shfl_xor(s, off);
        float ls = m + logf(s);
        if (node < n) {
            float* o = out + (size_t)node * DOUT + tx * 3;
            o[0] = l0 - ls;
            o[1] = l1 - ls;
            if (v2ok) o[2] = l2 - ls;
        }
    }
}

// ---------------------------------------------------------------------------
extern "C" void kernel_launch(void* const* d_in, const int* in_sizes, int n_in,
                              void* d_out, int out_size, void* d_ws, size_t ws_size,
                              hipStream_t stream) {
    const float* x     = (const float*)d_in[0];
    const int*   ei    = (const int*)d_in[1];
    const float* W1    = (const float*)d_in[2];
    const float* b1    = (const float*)d_in[3];
    const float* gamma = (const float*)d_in[4];
    const float* beta  = (const float*)d_in[5];
    const float* mean  = (const float*)d_in[6];
    const float* var   = (const float*)d_in[7];
    const float* W2    = (const float*)d_in[8];
    const float* b2    = (const float*)d_in[9];
    const float* Wf    = (const float*)d_in[10];
    const float* bf    = (const float*)d_in[11];
    float* out = (float*)d_out;

    int N_ = in_sizes[0] / 128;
    int E_ = in_sizes[1] / 2;
    const int* src = ei;
    const int* dst = ei + E_;

    char* ws = (char*)d_ws;
    unsigned* bufA = (unsigned*)ws; ws += (size_t)N_ * 64 * 4;  // bf16 table
    float* h1      = (float*)ws;  ws += (size_t)N_ * 128 * 4;
    int*   counts  = (int*)ws;    ws += (size_t)N_ * 4;
    int*   offsets = (int*)ws;    ws += (size_t)N_ * 4;
    int*   cursor  = (int*)ws;    ws += (size_t)N_ * 4;
    float* dinv    = (float*)ws;  ws += (size_t)N_ * 4;
    // padded CSR: sum((c+7)&~7) <= E + 7N; +64-rec tail for prefetch
    int2*  ew      = (int2*)ws;   ws += ((size_t)E_ + 7 * (size_t)N_ + 64) * 8;
    int*   bsums   = (int*)ws;    ws += 1024 * 4;
    unsigned* W1b  = (unsigned*)ws; ws += 128 * 64 * 4;         // bf16 W^T [n][k]
    unsigned* W2b  = (unsigned*)ws; ws += 128 * 64 * 4;

    int nb = (N_ + 1023) / 1024;
    int gemmBlocks = (N_ + 63) / 64;
    int edgeBlocks = (E_ + 1023) / 1024;  // 4 edges/thread

    zero_int_k<<<(N_ + 255) / 256, 256, 0, stream>>>(counts, N_);
    wprep_k<<<2, 256, 0, stream>>>(W1, W2, W1b, W2b);
    count4_k<<<edgeBlocks, 256, 0, stream>>>(dst, counts, E_, N_);
    scan1_k<<<nb, 256, 0, stream>>>(counts, offsets, bsums, N_);
    scan2_k<<<1, 128, 0, stream>>>(bsums, nb);
    finalize_k<<<(N_ + 255) / 256, 256, 0, stream>>>(offsets, cursor, dinv,
                                                     counts, bsums, ew, N_);
    fill4_k<<<edgeBlocks, 256, 0, stream>>>(src, dst, dinv, cursor, ew, E_);

    // layer 1
    gemm_mfma_k<<<gemmBlocks, 256, 0, stream>>>(x, W1b, bufA, N_);
    agg1_k<<<(N_ + 3) / 4, 256, 0, stream>>>(bufA, ew, offsets, counts, dinv,
                                             b1, gamma, beta, mean, var, h1, N_);
    // layer 2 (reuse bufA)
    gemm_mfma_k<<<gemmBlocks, 256, 0, stream>>>(h1, W2b, bufA, N_);
    agg2_k<<<(N_ + 3) / 4, 256, 0, stream>>>(bufA, ew, offsets, counts, dinv,
                                             b2, h1, N_);
    // head: h1 now holds jk = max(h1, h2); 64 nodes per block
    head_k<<<(N_ + 63) / 64, 256, 0, stream>>>(h1, Wf, bf, out, N_);
}

// Round 12
// 470.813 us; speedup vs baseline: 1.2283x; 1.2283x over previous
//
#include <hip/hip_runtime.h>
#include <math.h>

// Problem constants (from reference): N=100000, E=1600000, D_IN=D_H=128, D_OUT=47
#define DH 128
#define DOUT 47
#define BN_EPS 1e-5f

typedef __attribute__((ext_vector_type(8))) short short8;
typedef __attribute__((ext_vector_type(4))) float float4v;

// ---------------------------------------------------------------------------
// bf16 pack/unpack (RNE).
// ---------------------------------------------------------------------------
__device__ __forceinline__ unsigned bf16_rne(float f) {
    unsigned u = __float_as_uint(f);
    return (u + 0x7fffu + ((u >> 16) & 1u)) >> 16;
}
__device__ __forceinline__ unsigned pack_bf2(float a, float b) {
    return (bf16_rne(a) & 0xffffu) | (bf16_rne(b) << 16);
}
__device__ __forceinline__ float2 unpack_bf2(unsigned u) {
    return make_float2(__uint_as_float(u << 16),
                       __uint_as_float(u & 0xffff0000u));
}

// ---------------------------------------------------------------------------
// CSR build. Edge lists PADDED to multiple of 8 records per node.
// R11 lesson: atomic-with-return on contended cursors is THROUGHPUT-bound;
// batching doesn't help. So: the counting pass's atomicAdd return IS the
// edge's rank (any per-node slot permutation is valid for a sum); the
// scatter pass is then atomic-free.
// ---------------------------------------------------------------------------

__global__ void zero_int_k(int* __restrict__ p, int n) {
    int i = blockIdx.x * 256 + threadIdx.x;
    if (i < n) p[i] = 0;
}

// count + rank: rank[i] = old value of counts[dst[i]] (order irrelevant).
__global__ __launch_bounds__(256) void count_rank_k(const int* __restrict__ dst,
                                                    int* __restrict__ counts,
                                                    int* __restrict__ rank, int e) {
    int i0 = (blockIdx.x * 256 + threadIdx.x) * 4;
    if (i0 + 4 <= e) {
        int4 d4 = *(const int4*)(dst + i0);
        int4 r4;
        r4.x = atomicAdd(&counts[d4.x], 1);
        r4.y = atomicAdd(&counts[d4.y], 1);
        r4.z = atomicAdd(&counts[d4.z], 1);
        r4.w = atomicAdd(&counts[d4.w], 1);
        *(int4*)(rank + i0) = r4;
    } else {
        for (int i = i0; i < e; i++) rank[i] = atomicAdd(&counts[dst[i]], 1);
    }
}

// scan1 scans PADDED counts ((c+7)&~7).
__global__ __launch_bounds__(256) void scan1_k(const int* __restrict__ counts,
                                               int* __restrict__ offsets,
                                               int* __restrict__ blocksums, int n) {
    __shared__ int sd[256];
    int tid = threadIdx.x;
    int base = blockIdx.x * 1024 + tid * 4;
    int v0 = (base + 0 < n) ? ((counts[base + 0] + 7) & ~7) : 0;
    int v1 = (base + 1 < n) ? ((counts[base + 1] + 7) & ~7) : 0;
    int v2 = (base + 2 < n) ? ((counts[base + 2] + 7) & ~7) : 0;
    int v3 = (base + 3 < n) ? ((counts[base + 3] + 7) & ~7) : 0;
    int tsum = v0 + v1 + v2 + v3;
    sd[tid] = tsum;
    __syncthreads();
    for (int off = 1; off < 256; off <<= 1) {
        int x = (tid >= off) ? sd[tid - off] : 0;
        __syncthreads();
        sd[tid] += x;
        __syncthreads();
    }
    if (tid == 255) blocksums[blockIdx.x] = sd[255];
    int run = sd[tid] - tsum;
    if (base + 0 < n) offsets[base + 0] = run;  run += v0;
    if (base + 1 < n) offsets[base + 1] = run;  run += v1;
    if (base + 2 < n) offsets[base + 2] = run;  run += v2;
    if (base + 3 < n) offsets[base + 3] = run;
}

__global__ __launch_bounds__(128) void scan2_k(int* __restrict__ blocksums, int nb) {
    __shared__ int sd[128];
    int tid = threadIdx.x;
    int v = (tid < nb) ? blocksums[tid] : 0;
    sd[tid] = v;
    __syncthreads();
    for (int off = 1; off < 128; off <<= 1) {
        int x = (tid >= off) ? sd[tid - off] : 0;
        __syncthreads();
        sd[tid] += x;
        __syncthreads();
    }
    if (tid < nb) blocksums[tid] = sd[tid] - v;  // exclusive
}

// finalize: padded offsets, dinv, and writes the pad records.
__global__ void finalize_k(int* __restrict__ offsets,
                           float* __restrict__ dinv, const int* __restrict__ counts,
                           const int* __restrict__ blocksums,
                           int2* __restrict__ ew, int n) {
    int i = blockIdx.x * 256 + threadIdx.x;
    if (i >= n) return;
    int o = offsets[i] + blocksums[i >> 10];
    offsets[i] = o;
    int c = counts[i];
    dinv[i] = rsqrtf((float)(c + 1));  // +1 self-loop; deg>=1 always
    int cP = (c + 7) & ~7;
    int2 z; z.x = 0; z.y = 0;
    for (int j = o + c; j < o + cP; ++j) ew[j] = z;  // pad: row 0, weight 0
}

// scatter: atomic-free fill. slot = offsets[dst] + rank.
__global__ __launch_bounds__(256) void scatter_k(const int* __restrict__ src,
                                                 const int* __restrict__ dst,
                                                 const int* __restrict__ rank,
                                                 const int* __restrict__ offsets,
                                                 const float* __restrict__ dinv,
                                                 int2* __restrict__ ew, int e) {
    int i0 = (blockIdx.x * 256 + threadIdx.x) * 4;
    if (i0 + 4 <= e) {
        int4 s4 = *(const int4*)(src + i0);
        int4 d4 = *(const int4*)(dst + i0);
        int4 r4 = *(const int4*)(rank + i0);
        int sa[4] = {s4.x, s4.y, s4.z, s4.w};
        int da[4] = {d4.x, d4.y, d4.z, d4.w};
        int ra[4] = {r4.x, r4.y, r4.z, r4.w};
        int slot[4];
        float w[4];
#pragma unroll
        for (int k = 0; k < 4; k++) slot[k] = offsets[da[k]] + ra[k];
#pragma unroll
        for (int k = 0; k < 4; k++) w[k] = dinv[sa[k]] * dinv[da[k]];
#pragma unroll
        for (int k = 0; k < 4; k++) {
            int2 r; r.x = sa[k]; r.y = __float_as_int(w[k]);
            ew[slot[k]] = r;
        }
    } else {
        for (int i = i0; i < e; i++) {
            int s = src[i], d = dst[i];
            int2 r; r.x = s; r.y = __float_as_int(dinv[s] * dinv[d]);
            ew[offsets[d] + rank[i]] = r;
        }
    }
}

// ---------------------------------------------------------------------------
// Weight prep: W fp32 [k][n] -> bf16 transposed [n][k] (64 uints/row).
// ---------------------------------------------------------------------------
__global__ __launch_bounds__(256) void wprep_k(const float* __restrict__ W1,
                                               const float* __restrict__ W2,
                                               unsigned* __restrict__ W1b,
                                               unsigned* __restrict__ W2b) {
    const float* W = blockIdx.x ? W2 : W1;
    unsigned* Wb = blockIdx.x ? W2b : W1b;
    int tid = threadIdx.x;
    for (int p = tid; p < 128 * 32; p += 256) {
        int n = p >> 5;
        int k0 = (p & 31) << 2;
        float f0 = W[(size_t)(k0 + 0) * 128 + n];
        float f1 = W[(size_t)(k0 + 1) * 128 + n];
        float f2 = W[(size_t)(k0 + 2) * 128 + n];
        float f3 = W[(size_t)(k0 + 3) * 128 + n];
        uint2 v;
        v.x = pack_bf2(f0, f1);
        v.y = pack_bf2(f2, f3);
        *(uint2*)(Wb + (size_t)n * 64 + (k0 >> 1)) = v;
    }
}

// ---------------------------------------------------------------------------
// MFMA GEMM: C[M x 128] = A[M x 128] @ W[128 x 128], A fp32 split hi/lo bf16
// in-register, W bf16 [n][k] staged in LDS. Output packed bf16 table.
// ---------------------------------------------------------------------------
__global__ __launch_bounds__(256) void gemm_mfma_k(const float* __restrict__ A,
                                                   const unsigned* __restrict__ Wb,
                                                   unsigned* __restrict__ Cb, int M) {
    __shared__ ushort Bl[128 * 136];
    int tid = threadIdx.x;
    {
        unsigned* Bu = (unsigned*)Bl;
        for (int q = tid; q < 128 * 16; q += 256) {
            int row = q >> 4;
            int c = (q & 15) << 2;
            uint4 v = *(const uint4*)(Wb + (size_t)row * 64 + c);
            *(uint4*)(Bu + (size_t)row * 68 + c) = v;
        }
    }
    __syncthreads();

    int lane = tid & 63;
    int wv = tid >> 6;
    int quad = lane >> 4;
    int l15 = lane & 15;
    int r0 = blockIdx.x * 64 + wv * 16;
    int mload = r0 + l15;
    if (mload > M - 1) mload = M - 1;
    const float* Ar = A + (size_t)mload * 128 + quad * 8;

    float4v acc[8];
#pragma unroll
    for (int t = 0; t < 8; t++) acc[t] = (float4v){0.f, 0.f, 0.f, 0.f};

    for (int kp = 0; kp < 4; ++kp) {
        float4 a0 = *(const float4*)(Ar + kp * 32);
        float4 a1 = *(const float4*)(Ar + kp * 32 + 4);
        float af[8] = {a0.x, a0.y, a0.z, a0.w, a1.x, a1.y, a1.z, a1.w};
        short8 hi, lo;
#pragma unroll
        for (int j = 0; j < 8; j++) {
            unsigned h = bf16_rne(af[j]);
            hi[j] = (short)h;
            float res = af[j] - __uint_as_float(h << 16);
            lo[j] = (short)bf16_rne(res);
        }
        int kb = kp * 32 + quad * 8;
#pragma unroll
        for (int nt = 0; nt < 8; nt++) {
            short8 b8 = *(const short8*)(&Bl[(size_t)(nt * 16 + l15) * 136 + kb]);
            acc[nt] = __builtin_amdgcn_mfma_f32_16x16x32_bf16(hi, b8, acc[nt], 0, 0, 0);
            acc[nt] = __builtin_amdgcn_mfma_f32_16x16x32_bf16(lo, b8, acc[nt], 0, 0, 0);
        }
    }

    ushort* Cu = (ushort*)Cb;
#pragma unroll
    for (int r = 0; r < 4; r++) {
        int row = r0 + quad * 4 + r;
        if (row < M) {
#pragma unroll
            for (int nt = 0; nt < 8; nt++) {
                Cu[(size_t)row * 128 + nt * 16 + l15] = (ushort)bf16_rne(acc[nt][r]);
            }
        }
    }
}

// ---------------------------------------------------------------------------
// Aggregation core: one wave per node. Half-wave h handles edges 2k+h of each
// 8-edge group; lane loads uint2 (4 bf16 feats). Padded CSR -> no masking.
// ---------------------------------------------------------------------------
__device__ __forceinline__ float4 agg_core(const uint2* __restrict__ Hu2,
                                           const int2* __restrict__ ew,
                                           int start, int cnt, int node,
                                           int li, int half, float di) {
    float4 acc = make_float4(0.f, 0.f, 0.f, 0.f);
    int groups = ((cnt + 7) & ~7) >> 3;
    if (groups > 0) {
        const int2* p = ew + start + half;
        int2 r[4];
#pragma unroll
        for (int k = 0; k < 4; k++) r[k] = p[2 * k];
        for (int g = 0; g < groups; ++g) {
            uint2 gb[4];
#pragma unroll
            for (int k = 0; k < 4; k++)
                gb[k] = Hu2[(size_t)r[k].x * 32 + li];
            int2 rn[4];
            const int2* pn = p + 8 * (g + 1);
#pragma unroll
            for (int k = 0; k < 4; k++) rn[k] = pn[2 * k];
#pragma unroll
            for (int k = 0; k < 4; k++) {
                float w = __int_as_float(r[k].y);
                float2 f0 = unpack_bf2(gb[k].x);
                float2 f1 = unpack_bf2(gb[k].y);
                acc.x = fmaf(f0.x, w, acc.x);
                acc.y = fmaf(f0.y, w, acc.y);
                acc.z = fmaf(f1.x, w, acc.z);
                acc.w = fmaf(f1.y, w, acc.w);
            }
#pragma unroll
            for (int k = 0; k < 4; k++) r[k] = rn[k];
        }
    }
    acc.x += __shfl_xor(acc.x, 32);
    acc.y += __shfl_xor(acc.y, 32);
    acc.z += __shfl_xor(acc.z, 32);
    acc.w += __shfl_xor(acc.w, 32);
    uint2 sv = Hu2[(size_t)node * 32 + li];
    float ws = di * di;
    float2 s0 = unpack_bf2(sv.x);
    float2 s1 = unpack_bf2(sv.y);
    acc.x = fmaf(s0.x, ws, acc.x);
    acc.y = fmaf(s0.y, ws, acc.y);
    acc.z = fmaf(s1.x, ws, acc.z);
    acc.w = fmaf(s1.y, ws, acc.w);
    return acc;
}

// Layer 1: + b1, BN(eval), ReLU -> H1 (fp32)
__global__ __launch_bounds__(256) void agg1_k(
    const unsigned* __restrict__ H, const int2* __restrict__ ew,
    const int* __restrict__ offsets, const int* __restrict__ counts,
    const float* __restrict__ dinv, const float* __restrict__ b1,
    const float* __restrict__ gamma, const float* __restrict__ beta,
    const float* __restrict__ mean, const float* __restrict__ var,
    float* __restrict__ H1, int n) {
    int lane = threadIdx.x & 63;
    int li = lane & 31;
    int half = lane >> 5;
    int node = blockIdx.x * 4 + (threadIdx.x >> 6);
    if (node >= n) return;
    float4 acc = agg_core((const uint2*)H, ew, offsets[node], counts[node],
                          node, li, half, dinv[node]);
    if (half == 0) {
        int f0 = li * 4;
        float4 bb = *(const float4*)(b1 + f0);
        float4 mm = *(const float4*)(mean + f0);
        float4 vv = *(const float4*)(var + f0);
        float4 gg = *(const float4*)(gamma + f0);
        float4 be = *(const float4*)(beta + f0);
        float4 o;
        o.x = fmaxf((acc.x + bb.x - mm.x) * rsqrtf(vv.x + BN_EPS) * gg.x + be.x, 0.f);
        o.y = fmaxf((acc.y + bb.y - mm.y) * rsqrtf(vv.y + BN_EPS) * gg.y + be.y, 0.f);
        o.z = fmaxf((acc.z + bb.z - mm.z) * rsqrtf(vv.z + BN_EPS) * gg.z + be.z, 0.f);
        o.w = fmaxf((acc.w + bb.w - mm.w) * rsqrtf(vv.w + BN_EPS) * gg.w + be.w, 0.f);
        *(float4*)(H1 + (size_t)node * 128 + f0) = o;
    }
}

// Layer 2: + b2, then JK max with H1 (in-place H1 -> JK)
__global__ __launch_bounds__(256) void agg2_k(
    const unsigned* __restrict__ H, const int2* __restrict__ ew,
    const int* __restrict__ offsets, const int* __restrict__ counts,
    const float* __restrict__ dinv, const float* __restrict__ b2,
    float* __restrict__ H1JK, int n) {
    int lane = threadIdx.x & 63;
    int li = lane & 31;
    int half = lane >> 5;
    int node = blockIdx.x * 4 + (threadIdx.x >> 6);
    if (node >= n) return;
    float4 acc = agg_core((const uint2*)H, ew, offsets[node], counts[node],
                          node, li, half, dinv[node]);
    if (half == 0) {
        int f0 = li * 4;
        float4 bb = *(const float4*)(b2 + f0);
        float4* p = (float4*)(H1JK + (size_t)node * 128 + f0);
        float4 h1v = *p;
        float4 o;
        o.x = fmaxf(h1v.x, acc.x + bb.x);
        o.y = fmaxf(h1v.y, acc.y + bb.y);
        o.z = fmaxf(h1v.z, acc.z + bb.z);
        o.w = fmaxf(h1v.w, acc.w + bb.w);
        *p = o;
    }
}

// ---------------------------------------------------------------------------
// Head: tiled GEMM (64 nodes x 48 cols, K=128) + fused log_softmax.
// ---------------------------------------------------------------------------
__global__ __launch_bounds__(256) void head_k(const float* __restrict__ JK,
                                              const float* __restrict__ Wf,
                                              const float* __restrict__ bf,
                                              float* __restrict__ out, int n) {
    __shared__ __align__(16) float Bs[48 * 132];  // [col][k], stride 132
    __shared__ __align__(16) float As[64 * 36];   // [row][k-in-panel], stride 36
    int tid = threadIdx.x;
    for (int p = tid; p < 47 * 32; p += 256) {
        int c = p >> 5;          // 0..46
        int k0 = (p & 31) << 2;  // 0,4,...,124
        float4 v;
        v.x = Wf[(size_t)(k0 + 0) * DOUT + c];
        v.y = Wf[(size_t)(k0 + 1) * DOUT + c];
        v.z = Wf[(size_t)(k0 + 2) * DOUT + c];
        v.w = Wf[(size_t)(k0 + 3) * DOUT + c];
        *(float4*)(&Bs[c * 132 + k0]) = v;
    }
    int tx = tid & 15;   // col group: cols [3*tx, 3*tx+3)
    int ty = tid >> 4;   // row group: rows [4*ty, 4*ty+4)
    int node0 = blockIdx.x * 64;

    float acc[4][3];
#pragma unroll
    for (int i = 0; i < 4; i++)
#pragma unroll
        for (int j = 0; j < 3; j++) acc[i][j] = 0.f;

    for (int kk = 0; kk < 128; kk += 32) {
        __syncthreads();
        for (int l = tid; l < 512; l += 256) {
            int r = l >> 3;
            int c4 = (l & 7) << 2;
            int row = node0 + r;
            float4 v = make_float4(0.f, 0.f, 0.f, 0.f);
            if (row < n) v = *(const float4*)(JK + (size_t)row * 128 + kk + c4);
            *(float4*)(&As[r * 36 + c4]) = v;
        }
        __syncthreads();
#pragma unroll
        for (int k4 = 0; k4 < 32; k4 += 4) {
            float4 a0 = *(const float4*)(&As[(ty * 4 + 0) * 36 + k4]);
            float4 a1 = *(const float4*)(&As[(ty * 4 + 1) * 36 + k4]);
            float4 a2 = *(const float4*)(&As[(ty * 4 + 2) * 36 + k4]);
            float4 a3 = *(const float4*)(&As[(ty * 4 + 3) * 36 + k4]);
            float4 b0 = *(const float4*)(&Bs[(tx * 3 + 0) * 132 + kk + k4]);
            float4 b1 = *(const float4*)(&Bs[(tx * 3 + 1) * 132 + kk + k4]);
            float4 b2 = *(const float4*)(&Bs[(tx * 3 + 2) * 132 + kk + k4]);
#define DOT_ROW(i, a)                                                        \
            acc[i][0] = fmaf(a.x, b0.x, acc[i][0]);                          \
            acc[i][0] = fmaf(a.y, b0.y, acc[i][0]);                          \
            acc[i][0] = fmaf(a.z, b0.z, acc[i][0]);                          \
            acc[i][0] = fmaf(a.w, b0.w, acc[i][0]);                          \
            acc[i][1] = fmaf(a.x, b1.x, acc[i][1]);                          \
            acc[i][1] = fmaf(a.y, b1.y, acc[i][1]);                          \
            acc[i][1] = fmaf(a.z, b1.z, acc[i][1]);                          \
            acc[i][1] = fmaf(a.w, b1.w, acc[i][1]);                          \
            acc[i][2] = fmaf(a.x, b2.x, acc[i][2]);                          \
            acc[i][2] = fmaf(a.y, b2.y, acc[i][2]);                          \
            acc[i][2] = fmaf(a.z, b2.z, acc[i][2]);                          \
            acc[i][2] = fmaf(a.w, b2.w, acc[i][2]);
            DOT_ROW(0, a0)
            DOT_ROW(1, a1)
            DOT_ROW(2, a2)
            DOT_ROW(3, a3)
#undef DOT_ROW
        }
    }

    float bfv[3];
#pragma unroll
    for (int j = 0; j < 3; j++) {
        int c = tx * 3 + j;
        bfv[j] = (c < DOUT) ? bf[c] : 0.f;
    }
#pragma unroll
    for (int i = 0; i < 4; i++) {
        int node = node0 + ty * 4 + i;
        float l0 = acc[i][0] + bfv[0];
        float l1 = acc[i][1] + bfv[1];
        float l2 = acc[i][2] + bfv[2];
        bool v2ok = (tx * 3 + 2) < DOUT;  // only col 47 (tx=15,j=2) invalid
        float m = fmaxf(l0, l1);
        if (v2ok) m = fmaxf(m, l2);
        for (int off = 8; off >= 1; off >>= 1) m = fmaxf(m, __shfl_xor(m, off));
        float s = expf(l0 - m) + expf(l1 - m) + (v2ok ? expf(l2 - m) : 0.f);
        for (int off = 8; off >= 1; off >>= 1) s += __shfl_xor(s, off);
        float ls = m + logf(s);
        if (node < n) {
            float* o = out + (size_t)node * DOUT + tx * 3;
            o[0] = l0 - ls;
            o[1] = l1 - ls;
            if (v2ok) o[2] = l2 - ls;
        }
    }
}

// ---------------------------------------------------------------------------
extern "C" void kernel_launch(void* const* d_in, const int* in_sizes, int n_in,
                              void* d_out, int out_size, void* d_ws, size_t ws_size,
                              hipStream_t stream) {
    const float* x     = (const float*)d_in[0];
    const int*   ei    = (const int*)d_in[1];
    const float* W1    = (const float*)d_in[2];
    const float* b1    = (const float*)d_in[3];
    const float* gamma = (const float*)d_in[4];
    const float* beta  = (const float*)d_in[5];
    const float* mean  = (const float*)d_in[6];
    const float* var   = (const float*)d_in[7];
    const float* W2    = (const float*)d_in[8];
    const float* b2    = (const float*)d_in[9];
    const float* Wf    = (const float*)d_in[10];
    const float* bf    = (const float*)d_in[11];
    float* out = (float*)d_out;

    int N_ = in_sizes[0] / 128;
    int E_ = in_sizes[1] / 2;
    const int* src = ei;
    const int* dst = ei + E_;

    char* ws = (char*)d_ws;
    unsigned* bufA = (unsigned*)ws; ws += (size_t)N_ * 64 * 4;  // bf16 table
    float* h1      = (float*)ws;  ws += (size_t)N_ * 128 * 4;
    int*   counts  = (int*)ws;    ws += (size_t)N_ * 4;
    int*   offsets = (int*)ws;    ws += (size_t)N_ * 4;
    float* dinv    = (float*)ws;  ws += (size_t)N_ * 4;
    int*   rank    = (int*)ws;    ws += (size_t)E_ * 4;
    // padded CSR: sum((c+7)&~7) <= E + 7N; +64-rec tail for prefetch
    int2*  ew      = (int2*)ws;   ws += ((size_t)E_ + 7 * (size_t)N_ + 64) * 8;
    int*   bsums   = (int*)ws;    ws += 1024 * 4;
    unsigned* W1b  = (unsigned*)ws; ws += 128 * 64 * 4;         // bf16 W^T [n][k]
    unsigned* W2b  = (unsigned*)ws; ws += 128 * 64 * 4;

    int nb = (N_ + 1023) / 1024;
    int gemmBlocks = (N_ + 63) / 64;
    int edgeBlocks = (E_ + 1023) / 1024;  // 4 edges/thread

    zero_int_k<<<(N_ + 255) / 256, 256, 0, stream>>>(counts, N_);
    wprep_k<<<2, 256, 0, stream>>>(W1, W2, W1b, W2b);
    count_rank_k<<<edgeBlocks, 256, 0, stream>>>(dst, counts, rank, E_);
    scan1_k<<<nb, 256, 0, stream>>>(counts, offsets, bsums, N_);
    scan2_k<<<1, 128, 0, stream>>>(bsums, nb);
    finalize_k<<<(N_ + 255) / 256, 256, 0, stream>>>(offsets, dinv,
                                                     counts, bsums, ew, N_);
    scatter_k<<<edgeBlocks, 256, 0, stream>>>(src, dst, rank, offsets, dinv, ew, E_);

    // layer 1
    gemm_mfma_k<<<gemmBlocks, 256, 0, stream>>>(x, W1b, bufA, N_);
    agg1_k<<<(N_ + 3) / 4, 256, 0, stream>>>(bufA, ew, offsets, counts, dinv,
                                             b1, gamma, beta, mean, var, h1, N_);
    // layer 2 (reuse bufA)
    gemm_mfma_k<<<gemmBlocks, 256, 0, stream>>>(h1, W2b, bufA, N_);
    agg2_k<<<(N_ + 3) / 4, 256, 0, stream>>>(bufA, ew, offsets, counts, dinv,
                                             b2, h1, N_);
    // head: h1 now holds jk = max(h1, h2); 64 nodes per block
    head_k<<<(N_ + 63) / 64, 256, 0, stream>>>(h1, Wf, bf, out, N_);
}

// Round 13
// 461.334 us; speedup vs baseline: 1.2536x; 1.0205x over previous
//
#include <hip/hip_runtime.h>
#include <math.h>

// Problem constants (from reference): N=100000, E=1600000, D_IN=D_H=128, D_OUT=47
#define DH 128
#define DOUT 47
#define BN_EPS 1e-5f

typedef __attribute__((ext_vector_type(8))) short short8;
typedef __attribute__((ext_vector_type(4))) float float4v;

// ---------------------------------------------------------------------------
// bf16 pack/unpack (RNE).
// ---------------------------------------------------------------------------
__device__ __forceinline__ unsigned bf16_rne(float f) {
    unsigned u = __float_as_uint(f);
    return (u + 0x7fffu + ((u >> 16) & 1u)) >> 16;
}
__device__ __forceinline__ unsigned pack_bf2(float a, float b) {
    return (bf16_rne(a) & 0xffffu) | (bf16_rne(b) << 16);
}
__device__ __forceinline__ float2 unpack_bf2(unsigned u) {
    return make_float2(__uint_as_float(u << 16),
                       __uint_as_float(u & 0xffff0000u));
}

// ---------------------------------------------------------------------------
// CSR build. Edge lists PADDED to multiple of 8 records per node.
// count pass's atomicAdd return IS the edge's rank; scatter is atomic-free.
// ---------------------------------------------------------------------------

__global__ void zero_int_k(int* __restrict__ p, int n) {
    int i = blockIdx.x * 256 + threadIdx.x;
    if (i < n) p[i] = 0;
}

__global__ __launch_bounds__(256) void count_rank_k(const int* __restrict__ dst,
                                                    int* __restrict__ counts,
                                                    int* __restrict__ rank, int e) {
    int i0 = (blockIdx.x * 256 + threadIdx.x) * 4;
    if (i0 + 4 <= e) {
        int4 d4 = *(const int4*)(dst + i0);
        int4 r4;
        r4.x = atomicAdd(&counts[d4.x], 1);
        r4.y = atomicAdd(&counts[d4.y], 1);
        r4.z = atomicAdd(&counts[d4.z], 1);
        r4.w = atomicAdd(&counts[d4.w], 1);
        *(int4*)(rank + i0) = r4;
    } else {
        for (int i = i0; i < e; i++) rank[i] = atomicAdd(&counts[dst[i]], 1);
    }
}

// scan1 scans PADDED counts ((c+7)&~7).
__global__ __launch_bounds__(256) void scan1_k(const int* __restrict__ counts,
                                               int* __restrict__ offsets,
                                               int* __restrict__ blocksums, int n) {
    __shared__ int sd[256];
    int tid = threadIdx.x;
    int base = blockIdx.x * 1024 + tid * 4;
    int v0 = (base + 0 < n) ? ((counts[base + 0] + 7) & ~7) : 0;
    int v1 = (base + 1 < n) ? ((counts[base + 1] + 7) & ~7) : 0;
    int v2 = (base + 2 < n) ? ((counts[base + 2] + 7) & ~7) : 0;
    int v3 = (base + 3 < n) ? ((counts[base + 3] + 7) & ~7) : 0;
    int tsum = v0 + v1 + v2 + v3;
    sd[tid] = tsum;
    __syncthreads();
    for (int off = 1; off < 256; off <<= 1) {
        int x = (tid >= off) ? sd[tid - off] : 0;
        __syncthreads();
        sd[tid] += x;
        __syncthreads();
    }
    if (tid == 255) blocksums[blockIdx.x] = sd[255];
    int run = sd[tid] - tsum;
    if (base + 0 < n) offsets[base + 0] = run;  run += v0;
    if (base + 1 < n) offsets[base + 1] = run;  run += v1;
    if (base + 2 < n) offsets[base + 2] = run;  run += v2;
    if (base + 3 < n) offsets[base + 3] = run;
}

__global__ __launch_bounds__(128) void scan2_k(int* __restrict__ blocksums, int nb) {
    __shared__ int sd[128];
    int tid = threadIdx.x;
    int v = (tid < nb) ? blocksums[tid] : 0;
    sd[tid] = v;
    __syncthreads();
    for (int off = 1; off < 128; off <<= 1) {
        int x = (tid >= off) ? sd[tid - off] : 0;
        __syncthreads();
        sd[tid] += x;
        __syncthreads();
    }
    if (tid < nb) blocksums[tid] = sd[tid] - v;  // exclusive
}

// finalize: padded offsets, dinv, and writes the pad records.
__global__ void finalize_k(int* __restrict__ offsets,
                           float* __restrict__ dinv, const int* __restrict__ counts,
                           const int* __restrict__ blocksums,
                           int2* __restrict__ ew, int n) {
    int i = blockIdx.x * 256 + threadIdx.x;
    if (i >= n) return;
    int o = offsets[i] + blocksums[i >> 10];
    offsets[i] = o;
    int c = counts[i];
    dinv[i] = rsqrtf((float)(c + 1));  // +1 self-loop; deg>=1 always
    int cP = (c + 7) & ~7;
    int2 z; z.x = 0; z.y = 0;
    for (int j = o + c; j < o + cP; ++j) ew[j] = z;  // pad: row 0, weight 0
}

// scatter: atomic-free fill. slot = offsets[dst] + rank.
__global__ __launch_bounds__(256) void scatter_k(const int* __restrict__ src,
                                                 const int* __restrict__ dst,
                                                 const int* __restrict__ rank,
                                                 const int* __restrict__ offsets,
                                                 const float* __restrict__ dinv,
                                                 int2* __restrict__ ew, int e) {
    int i0 = (blockIdx.x * 256 + threadIdx.x) * 4;
    if (i0 + 4 <= e) {
        int4 s4 = *(const int4*)(src + i0);
        int4 d4 = *(const int4*)(dst + i0);
        int4 r4 = *(const int4*)(rank + i0);
        int sa[4] = {s4.x, s4.y, s4.z, s4.w};
        int da[4] = {d4.x, d4.y, d4.z, d4.w};
        int ra[4] = {r4.x, r4.y, r4.z, r4.w};
        int slot[4];
        float w[4];
#pragma unroll
        for (int k = 0; k < 4; k++) slot[k] = offsets[da[k]] + ra[k];
#pragma unroll
        for (int k = 0; k < 4; k++) w[k] = dinv[sa[k]] * dinv[da[k]];
#pragma unroll
        for (int k = 0; k < 4; k++) {
            int2 r; r.x = sa[k]; r.y = __float_as_int(w[k]);
            ew[slot[k]] = r;
        }
    } else {
        for (int i = i0; i < e; i++) {
            int s = src[i], d = dst[i];
            int2 r; r.x = s; r.y = __float_as_int(dinv[s] * dinv[d]);
            ew[offsets[d] + rank[i]] = r;
        }
    }
}

// ---------------------------------------------------------------------------
// Weight prep: W fp32 [k][n] -> bf16 transposed [n][k] (64 uints/row).
// ---------------------------------------------------------------------------
__global__ __launch_bounds__(256) void wprep_k(const float* __restrict__ W1,
                                               const float* __restrict__ W2,
                                               unsigned* __restrict__ W1b,
                                               unsigned* __restrict__ W2b) {
    const float* W = blockIdx.x ? W2 : W1;
    unsigned* Wb = blockIdx.x ? W2b : W1b;
    int tid = threadIdx.x;
    for (int p = tid; p < 128 * 32; p += 256) {
        int n = p >> 5;
        int k0 = (p & 31) << 2;
        float f0 = W[(size_t)(k0 + 0) * 128 + n];
        float f1 = W[(size_t)(k0 + 1) * 128 + n];
        float f2 = W[(size_t)(k0 + 2) * 128 + n];
        float f3 = W[(size_t)(k0 + 3) * 128 + n];
        uint2 v;
        v.x = pack_bf2(f0, f1);
        v.y = pack_bf2(f2, f3);
        *(uint2*)(Wb + (size_t)n * 64 + (k0 >> 1)) = v;
    }
}

// ---------------------------------------------------------------------------
// MFMA GEMM (layer 1): A fp32 split hi/lo bf16 in-register (2 mfma/tile ->
// near-fp32 A), W bf16 [n][k] in LDS. Output packed bf16 table.
// ---------------------------------------------------------------------------
__global__ __launch_bounds__(256) void gemm_mfma_k(const float* __restrict__ A,
                                                   const unsigned* __restrict__ Wb,
                                                   unsigned* __restrict__ Cb, int M) {
    __shared__ ushort Bl[128 * 136];
    int tid = threadIdx.x;
    {
        unsigned* Bu = (unsigned*)Bl;
        for (int q = tid; q < 128 * 16; q += 256) {
            int row = q >> 4;
            int c = (q & 15) << 2;
            uint4 v = *(const uint4*)(Wb + (size_t)row * 64 + c);
            *(uint4*)(Bu + (size_t)row * 68 + c) = v;
        }
    }
    __syncthreads();

    int lane = tid & 63;
    int wv = tid >> 6;
    int quad = lane >> 4;
    int l15 = lane & 15;
    int r0 = blockIdx.x * 64 + wv * 16;
    int mload = r0 + l15;
    if (mload > M - 1) mload = M - 1;
    const float* Ar = A + (size_t)mload * 128 + quad * 8;

    float4v acc[8];
#pragma unroll
    for (int t = 0; t < 8; t++) acc[t] = (float4v){0.f, 0.f, 0.f, 0.f};

    for (int kp = 0; kp < 4; ++kp) {
        float4 a0 = *(const float4*)(Ar + kp * 32);
        float4 a1 = *(const float4*)(Ar + kp * 32 + 4);
        float af[8] = {a0.x, a0.y, a0.z, a0.w, a1.x, a1.y, a1.z, a1.w};
        short8 hi, lo;
#pragma unroll
        for (int j = 0; j < 8; j++) {
            unsigned h = bf16_rne(af[j]);
            hi[j] = (short)h;
            float res = af[j] - __uint_as_float(h << 16);
            lo[j] = (short)bf16_rne(res);
        }
        int kb = kp * 32 + quad * 8;
#pragma unroll
        for (int nt = 0; nt < 8; nt++) {
            short8 b8 = *(const short8*)(&Bl[(size_t)(nt * 16 + l15) * 136 + kb]);
            acc[nt] = __builtin_amdgcn_mfma_f32_16x16x32_bf16(hi, b8, acc[nt], 0, 0, 0);
            acc[nt] = __builtin_amdgcn_mfma_f32_16x16x32_bf16(lo, b8, acc[nt], 0, 0, 0);
        }
    }

    ushort* Cu = (ushort*)Cb;
#pragma unroll
    for (int r = 0; r < 4; r++) {
        int row = r0 + quad * 4 + r;
        if (row < M) {
#pragma unroll
            for (int nt = 0; nt < 8; nt++) {
                Cu[(size_t)row * 128 + nt * 16 + l15] = (ushort)bf16_rne(acc[nt][r]);
            }
        }
    }
}

// ---------------------------------------------------------------------------
// MFMA GEMM (layer 2): A is ALREADY bf16 packed [M][64 uints] -> single mfma
// per tile (no hi/lo needed; A exactly representable), half the A fetch.
// ---------------------------------------------------------------------------
__global__ __launch_bounds__(256) void gemm_bf16_k(const unsigned* __restrict__ Ab,
                                                   const unsigned* __restrict__ Wb,
                                                   unsigned* __restrict__ Cb, int M) {
    __shared__ ushort Bl[128 * 136];
    int tid = threadIdx.x;
    {
        unsigned* Bu = (unsigned*)Bl;
        for (int q = tid; q < 128 * 16; q += 256) {
            int row = q >> 4;
            int c = (q & 15) << 2;
            uint4 v = *(const uint4*)(Wb + (size_t)row * 64 + c);
            *(uint4*)(Bu + (size_t)row * 68 + c) = v;
        }
    }
    __syncthreads();

    int lane = tid & 63;
    int wv = tid >> 6;
    int quad = lane >> 4;
    int l15 = lane & 15;
    int r0 = blockIdx.x * 64 + wv * 16;
    int mload = r0 + l15;
    if (mload > M - 1) mload = M - 1;
    const unsigned* Ar = Ab + (size_t)mload * 64 + quad * 4;  // 8 bf16 = 4 uints

    float4v acc[8];
#pragma unroll
    for (int t = 0; t < 8; t++) acc[t] = (float4v){0.f, 0.f, 0.f, 0.f};

    for (int kp = 0; kp < 4; ++kp) {
        uint4 a4 = *(const uint4*)(Ar + kp * 16);  // k-offset kp*32 bf16
        short8 av;
        av[0] = (short)(a4.x & 0xffff); av[1] = (short)(a4.x >> 16);
        av[2] = (short)(a4.y & 0xffff); av[3] = (short)(a4.y >> 16);
        av[4] = (short)(a4.z & 0xffff); av[5] = (short)(a4.z >> 16);
        av[6] = (short)(a4.w & 0xffff); av[7] = (short)(a4.w >> 16);
        int kb = kp * 32 + quad * 8;
#pragma unroll
        for (int nt = 0; nt < 8; nt++) {
            short8 b8 = *(const short8*)(&Bl[(size_t)(nt * 16 + l15) * 136 + kb]);
            acc[nt] = __builtin_amdgcn_mfma_f32_16x16x32_bf16(av, b8, acc[nt], 0, 0, 0);
        }
    }

    ushort* Cu = (ushort*)Cb;
#pragma unroll
    for (int r = 0; r < 4; r++) {
        int row = r0 + quad * 4 + r;
        if (row < M) {
#pragma unroll
            for (int nt = 0; nt < 8; nt++) {
                Cu[(size_t)row * 128 + nt * 16 + l15] = (ushort)bf16_rne(acc[nt][r]);
            }
        }
    }
}

// ---------------------------------------------------------------------------
// Aggregation core: one wave per node. Half-wave h handles edges 2k+h of each
// 8-edge group; lane loads uint2 (4 bf16 feats). Padded CSR -> no masking.
// ---------------------------------------------------------------------------
__device__ __forceinline__ float4 agg_core(const uint2* __restrict__ Hu2,
                                           const int2* __restrict__ ew,
                                           int start, int cnt, int node,
                                           int li, int half, float di) {
    float4 acc = make_float4(0.f, 0.f, 0.f, 0.f);
    int groups = ((cnt + 7) & ~7) >> 3;
    if (groups > 0) {
        const int2* p = ew + start + half;
        int2 r[4];
#pragma unroll
        for (int k = 0; k < 4; k++) r[k] = p[2 * k];
        for (int g = 0; g < groups; ++g) {
            uint2 gb[4];
#pragma unroll
            for (int k = 0; k < 4; k++)
                gb[k] = Hu2[(size_t)r[k].x * 32 + li];
            int2 rn[4];
            const int2* pn = p + 8 * (g + 1);
#pragma unroll
            for (int k = 0; k < 4; k++) rn[k] = pn[2 * k];
#pragma unroll
            for (int k = 0; k < 4; k++) {
                float w = __int_as_float(r[k].y);
                float2 f0 = unpack_bf2(gb[k].x);
                float2 f1 = unpack_bf2(gb[k].y);
                acc.x = fmaf(f0.x, w, acc.x);
                acc.y = fmaf(f0.y, w, acc.y);
                acc.z = fmaf(f1.x, w, acc.z);
                acc.w = fmaf(f1.y, w, acc.w);
            }
#pragma unroll
            for (int k = 0; k < 4; k++) r[k] = rn[k];
        }
    }
    acc.x += __shfl_xor(acc.x, 32);
    acc.y += __shfl_xor(acc.y, 32);
    acc.z += __shfl_xor(acc.z, 32);
    acc.w += __shfl_xor(acc.w, 32);
    uint2 sv = Hu2[(size_t)node * 32 + li];
    float ws = di * di;
    float2 s0 = unpack_bf2(sv.x);
    float2 s1 = unpack_bf2(sv.y);
    acc.x = fmaf(s0.x, ws, acc.x);
    acc.y = fmaf(s0.y, ws, acc.y);
    acc.z = fmaf(s1.x, ws, acc.z);
    acc.w = fmaf(s1.y, ws, acc.w);
    return acc;
}

// Layer 1: + b1, BN(eval), ReLU -> H1 packed bf16
__global__ __launch_bounds__(256) void agg1_k(
    const unsigned* __restrict__ H, const int2* __restrict__ ew,
    const int* __restrict__ offsets, const int* __restrict__ counts,
    const float* __restrict__ dinv, const float* __restrict__ b1,
    const float* __restrict__ gamma, const float* __restrict__ beta,
    const float* __restrict__ mean, const float* __restrict__ var,
    unsigned* __restrict__ H1b, int n) {
    int lane = threadIdx.x & 63;
    int li = lane & 31;
    int half = lane >> 5;
    int node = blockIdx.x * 4 + (threadIdx.x >> 6);
    if (node >= n) return;
    float4 acc = agg_core((const uint2*)H, ew, offsets[node], counts[node],
                          node, li, half, dinv[node]);
    if (half == 0) {
        int f0 = li * 4;
        float4 bb = *(const float4*)(b1 + f0);
        float4 mm = *(const float4*)(mean + f0);
        float4 vv = *(const float4*)(var + f0);
        float4 gg = *(const float4*)(gamma + f0);
        float4 be = *(const float4*)(beta + f0);
        float4 o;
        o.x = fmaxf((acc.x + bb.x - mm.x) * rsqrtf(vv.x + BN_EPS) * gg.x + be.x, 0.f);
        o.y = fmaxf((acc.y + bb.y - mm.y) * rsqrtf(vv.y + BN_EPS) * gg.y + be.y, 0.f);
        o.z = fmaxf((acc.z + bb.z - mm.z) * rsqrtf(vv.z + BN_EPS) * gg.z + be.z, 0.f);
        o.w = fmaxf((acc.w + bb.w - mm.w) * rsqrtf(vv.w + BN_EPS) * gg.w + be.w, 0.f);
        uint2 pk;
        pk.x = pack_bf2(o.x, o.y);
        pk.y = pack_bf2(o.z, o.w);
        *(uint2*)(H1b + (size_t)node * 64 + li * 2) = pk;
    }
}

// Layer 2: + b2, then JK max with H1 (in-place on bf16 H1 -> JK)
__global__ __launch_bounds__(256) void agg2_k(
    const unsigned* __restrict__ H, const int2* __restrict__ ew,
    const int* __restrict__ offsets, const int* __restrict__ counts,
    const float* __restrict__ dinv, const float* __restrict__ b2,
    unsigned* __restrict__ H1b, int n) {
    int lane = threadIdx.x & 63;
    int li = lane & 31;
    int half = lane >> 5;
    int node = blockIdx.x * 4 + (threadIdx.x >> 6);
    if (node >= n) return;
    float4 acc = agg_core((const uint2*)H, ew, offsets[node], counts[node],
                          node, li, half, dinv[node]);
    if (half == 0) {
        int f0 = li * 4;
        float4 bb = *(const float4*)(b2 + f0);
        uint2* p = (uint2*)(H1b + (size_t)node * 64 + li * 2);
        uint2 hv = *p;
        float2 ha = unpack_bf2(hv.x);
        float2 hb = unpack_bf2(hv.y);
        float4 o;
        o.x = fmaxf(ha.x, acc.x + bb.x);
        o.y = fmaxf(ha.y, acc.y + bb.y);
        o.z = fmaxf(hb.x, acc.z + bb.z);
        o.w = fmaxf(hb.y, acc.w + bb.w);
        uint2 pk;
        pk.x = pack_bf2(o.x, o.y);
        pk.y = pack_bf2(o.z, o.w);
        *p = pk;
    }
}

// ---------------------------------------------------------------------------
// Head: tiled GEMM (64 nodes x 48 cols, K=128) + fused log_softmax.
// JK input is packed bf16 [n][64 uints].
// ---------------------------------------------------------------------------
__global__ __launch_bounds__(256) void head_k(const unsigned* __restrict__ JKb,
                                              const float* __restrict__ Wf,
                                              const float* __restrict__ bf,
                                              float* __restrict__ out, int n) {
    __shared__ __align__(16) float Bs[48 * 132];  // [col][k], stride 132
    __shared__ __align__(16) float As[64 * 36];   // [row][k-in-panel], stride 36
    int tid = threadIdx.x;
    for (int p = tid; p < 47 * 32; p += 256) {
        int c = p >> 5;          // 0..46
        int k0 = (p & 31) << 2;  // 0,4,...,124
        float4 v;
        v.x = Wf[(size_t)(k0 + 0) * DOUT + c];
        v.y = Wf[(size_t)(k0 + 1) * DOUT + c];
        v.z = Wf[(size_t)(k0 + 2) * DOUT + c];
        v.w = Wf[(size_t)(k0 + 3) * DOUT + c];
        *(float4*)(&Bs[c * 132 + k0]) = v;
    }
    int tx = tid & 15;   // col group: cols [3*tx, 3*tx+3)
    int ty = tid >> 4;   // row group: rows [4*ty, 4*ty+4)
    int node0 = blockIdx.x * 64;

    float acc[4][3];
#pragma unroll
    for (int i = 0; i < 4; i++)
#pragma unroll
        for (int j = 0; j < 3; j++) acc[i][j] = 0.f;

    for (int kk = 0; kk < 128; kk += 32) {
        __syncthreads();
        for (int l = tid; l < 512; l += 256) {
            int r = l >> 3;
            int c4 = (l & 7) << 2;
            int row = node0 + r;
            float4 v = make_float4(0.f, 0.f, 0.f, 0.f);
            if (row < n) {
                uint2 u = *(const uint2*)(JKb + (size_t)row * 64 + ((kk + c4) >> 1));
                float2 f0 = unpack_bf2(u.x);
                float2 f1 = unpack_bf2(u.y);
                v = make_float4(f0.x, f0.y, f1.x, f1.y);
            }
            *(float4*)(&As[r * 36 + c4]) = v;
        }
        __syncthreads();
#pragma unroll
        for (int k4 = 0; k4 < 32; k4 += 4) {
            float4 a0 = *(const float4*)(&As[(ty * 4 + 0) * 36 + k4]);
            float4 a1 = *(const float4*)(&As[(ty * 4 + 1) * 36 + k4]);
            float4 a2 = *(const float4*)(&As[(ty * 4 + 2) * 36 + k4]);
            float4 a3 = *(const float4*)(&As[(ty * 4 + 3) * 36 + k4]);
            float4 b0 = *(const float4*)(&Bs[(tx * 3 + 0) * 132 + kk + k4]);
            float4 b1 = *(const float4*)(&Bs[(tx * 3 + 1) * 132 + kk + k4]);
            float4 b2 = *(const float4*)(&Bs[(tx * 3 + 2) * 132 + kk + k4]);
#define DOT_ROW(i, a)                                                        \
            acc[i][0] = fmaf(a.x, b0.x, acc[i][0]);                          \
            acc[i][0] = fmaf(a.y, b0.y, acc[i][0]);                          \
            acc[i][0] = fmaf(a.z, b0.z, acc[i][0]);                          \
            acc[i][0] = fmaf(a.w, b0.w, acc[i][0]);                          \
            acc[i][1] = fmaf(a.x, b1.x, acc[i][1]);                          \
            acc[i][1] = fmaf(a.y, b1.y, acc[i][1]);                          \
            acc[i][1] = fmaf(a.z, b1.z, acc[i][1]);                          \
            acc[i][1] = fmaf(a.w, b1.w, acc[i][1]);                          \
            acc[i][2] = fmaf(a.x, b2.x, acc[i][2]);                          \
            acc[i][2] = fmaf(a.y, b2.y, acc[i][2]);                          \
            acc[i][2] = fmaf(a.z, b2.z, acc[i][2]);                          \
            acc[i][2] = fmaf(a.w, b2.w, acc[i][2]);
            DOT_ROW(0, a0)
            DOT_ROW(1, a1)
            DOT_ROW(2, a2)
            DOT_ROW(3, a3)
#undef DOT_ROW
        }
    }

    float bfv[3];
#pragma unroll
    for (int j = 0; j < 3; j++) {
        int c = tx * 3 + j;
        bfv[j] = (c < DOUT) ? bf[c] : 0.f;
    }
#pragma unroll
    for (int i = 0; i < 4; i++) {
        int node = node0 + ty * 4 + i;
        float l0 = acc[i][0] + bfv[0];
        float l1 = acc[i][1] + bfv[1];
        float l2 = acc[i][2] + bfv[2];
        bool v2ok = (tx * 3 + 2) < DOUT;  // only col 47 (tx=15,j=2) invalid
        float m = fmaxf(l0, l1);
        if (v2ok) m = fmaxf(m, l2);
        for (int off = 8; off >= 1; off >>= 1) m = fmaxf(m, __shfl_xor(m, off));
        float s = expf(l0 - m) + expf(l1 - m) + (v2ok ? expf(l2 - m) : 0.f);
        for (int off = 8; off >= 1; off >>= 1) s += __shfl_xor(s, off);
        float ls = m + logf(s);
        if (node < n) {
            float* o = out + (size_t)node * DOUT + tx * 3;
            o[0] = l0 - ls;
            o[1] = l1 - ls;
            if (v2ok) o[2] = l2 - ls;
        }
    }
}

// ---------------------------------------------------------------------------
extern "C" void kernel_launch(void* const* d_in, const int* in_sizes, int n_in,
                              void* d_out, int out_size, void* d_ws, size_t ws_size,
                              hipStream_t stream) {
    const float* x     = (const float*)d_in[0];
    const int*   ei    = (const int*)d_in[1];
    const float* W1    = (const float*)d_in[2];
    const float* b1    = (const float*)d_in[3];
    const float* gamma = (const float*)d_in[4];
    const float* beta  = (const float*)d_in[5];
    const float* mean  = (const float*)d_in[6];
    const float* var   = (const float*)d_in[7];
    const float* W2    = (const float*)d_in[8];
    const float* b2    = (const float*)d_in[9];
    const float* Wf    = (const float*)d_in[10];
    const float* bf    = (const float*)d_in[11];
    float* out = (float*)d_out;

    int N_ = in_sizes[0] / 128;
    int E_ = in_sizes[1] / 2;
    const int* src = ei;
    const int* dst = ei + E_;

    char* ws = (char*)d_ws;
    unsigned* bufA = (unsigned*)ws; ws += (size_t)N_ * 64 * 4;  // bf16 gather table
    unsigned* h1b  = (unsigned*)ws; ws += (size_t)N_ * 64 * 4;  // bf16 h1 / JK
    int*   counts  = (int*)ws;    ws += (size_t)N_ * 4;
    int*   offsets = (int*)ws;    ws += (size_t)N_ * 4;
    float* dinv    = (float*)ws;  ws += (size_t)N_ * 4;
    int*   rank    = (int*)ws;    ws += (size_t)E_ * 4;
    // padded CSR: sum((c+7)&~7) <= E + 7N; +64-rec tail for prefetch
    int2*  ew      = (int2*)ws;   ws += ((size_t)E_ + 7 * (size_t)N_ + 64) * 8;
    int*   bsums   = (int*)ws;    ws += 1024 * 4;
    unsigned* W1b  = (unsigned*)ws; ws += 128 * 64 * 4;         // bf16 W^T [n][k]
    unsigned* W2b  = (unsigned*)ws; ws += 128 * 64 * 4;

    int nb = (N_ + 1023) / 1024;
    int gemmBlocks = (N_ + 63) / 64;
    int edgeBlocks = (E_ + 1023) / 1024;  // 4 edges/thread

    zero_int_k<<<(N_ + 255) / 256, 256, 0, stream>>>(counts, N_);
    wprep_k<<<2, 256, 0, stream>>>(W1, W2, W1b, W2b);
    count_rank_k<<<edgeBlocks, 256, 0, stream>>>(dst, counts, rank, E_);
    scan1_k<<<nb, 256, 0, stream>>>(counts, offsets, bsums, N_);
    scan2_k<<<1, 128, 0, stream>>>(bsums, nb);
    finalize_k<<<(N_ + 255) / 256, 256, 0, stream>>>(offsets, dinv,
                                                     counts, bsums, ew, N_);
    scatter_k<<<edgeBlocks, 256, 0, stream>>>(src, dst, rank, offsets, dinv, ew, E_);

    // layer 1
    gemm_mfma_k<<<gemmBlocks, 256, 0, stream>>>(x, W1b, bufA, N_);
    agg1_k<<<(N_ + 3) / 4, 256, 0, stream>>>(bufA, ew, offsets, counts, dinv,
                                             b1, gamma, beta, mean, var, h1b, N_);
    // layer 2 (bf16 A -> single-mfma gemm)
    gemm_bf16_k<<<gemmBlocks, 256, 0, stream>>>(h1b, W2b, bufA, N_);
    agg2_k<<<(N_ + 3) / 4, 256, 0, stream>>>(bufA, ew, offsets, counts, dinv,
                                             b2, h1b, N_);
    // head: h1b now holds jk = max(h1, h2) in bf16; 64 nodes per block
    head_k<<<(N_ + 63) / 64, 256, 0, stream>>>(h1b, Wf, bf, out, N_);
}

// Round 14
// 424.952 us; speedup vs baseline: 1.3609x; 1.0856x over previous
//
#include <hip/hip_runtime.h>
#include <math.h>

// Problem constants (from reference): N=100000, E=1600000, D_IN=D_H=128, D_OUT=47
#define DH 128
#define DOUT 47
#define BN_EPS 1e-5f

typedef __attribute__((ext_vector_type(8))) short short8;
typedef __attribute__((ext_vector_type(4))) float float4v;

// ---------------------------------------------------------------------------
// bf16 pack/unpack (RNE).
// ---------------------------------------------------------------------------
__device__ __forceinline__ unsigned bf16_rne(float f) {
    unsigned u = __float_as_uint(f);
    return (u + 0x7fffu + ((u >> 16) & 1u)) >> 16;
}
__device__ __forceinline__ unsigned pack_bf2(float a, float b) {
    return (bf16_rne(a) & 0xffffu) | (bf16_rne(b) << 16);
}
__device__ __forceinline__ float2 unpack_bf2(unsigned u) {
    return make_float2(__uint_as_float(u << 16),
                       __uint_as_float(u & 0xffff0000u));
}

// ---------------------------------------------------------------------------
// Pre-scaled-table GCN: table row g[s] = dinv[s] * (X@W)[s] (scaled in GEMM
// epilogue), so h[d] = dinv[d] * (sum_{s in N(d)} g[s] + g[d]). Edge record
// is then just a 4-B src index; pads point at zeroed sentinel row N.
// ---------------------------------------------------------------------------

// prep: block 0 -> W1 transpose+bf16 (+ zero sentinel row of bufA),
//       block 1 -> W2, blocks >=2 -> zero counts.
__global__ __launch_bounds__(256) void prep_k(const float* __restrict__ W1,
                                              const float* __restrict__ W2,
                                              unsigned* __restrict__ W1b,
                                              unsigned* __restrict__ W2b,
                                              int* __restrict__ counts,
                                              unsigned* __restrict__ bufA, int n) {
    int tid = threadIdx.x;
    if (blockIdx.x >= 2) {
        int i = (blockIdx.x - 2) * 256 + tid;
        if (i < n) counts[i] = 0;
        return;
    }
    const float* W = blockIdx.x ? W2 : W1;
    unsigned* Wb = blockIdx.x ? W2b : W1b;
    if (blockIdx.x == 0 && tid < 64) bufA[(size_t)n * 64 + tid] = 0;  // sentinel row
    for (int p = tid; p < 128 * 32; p += 256) {
        int nn = p >> 5;
        int k0 = (p & 31) << 2;
        float f0 = W[(size_t)(k0 + 0) * 128 + nn];
        float f1 = W[(size_t)(k0 + 1) * 128 + nn];
        float f2 = W[(size_t)(k0 + 2) * 128 + nn];
        float f3 = W[(size_t)(k0 + 3) * 128 + nn];
        uint2 v;
        v.x = pack_bf2(f0, f1);
        v.y = pack_bf2(f2, f3);
        *(uint2*)(Wb + (size_t)nn * 64 + (k0 >> 1)) = v;
    }
}

__global__ __launch_bounds__(256) void count_rank_k(const int* __restrict__ dst,
                                                    int* __restrict__ counts,
                                                    int* __restrict__ rank, int e) {
    int i0 = (blockIdx.x * 256 + threadIdx.x) * 4;
    if (i0 + 4 <= e) {
        int4 d4 = *(const int4*)(dst + i0);
        int4 r4;
        r4.x = atomicAdd(&counts[d4.x], 1);
        r4.y = atomicAdd(&counts[d4.y], 1);
        r4.z = atomicAdd(&counts[d4.z], 1);
        r4.w = atomicAdd(&counts[d4.w], 1);
        *(int4*)(rank + i0) = r4;
    } else {
        for (int i = i0; i < e; i++) rank[i] = atomicAdd(&counts[dst[i]], 1);
    }
}

// scan1 scans PADDED counts ((c+7)&~7).
__global__ __launch_bounds__(256) void scan1_k(const int* __restrict__ counts,
                                               int* __restrict__ offsets,
                                               int* __restrict__ blocksums, int n) {
    __shared__ int sd[256];
    int tid = threadIdx.x;
    int base = blockIdx.x * 1024 + tid * 4;
    int v0 = (base + 0 < n) ? ((counts[base + 0] + 7) & ~7) : 0;
    int v1 = (base + 1 < n) ? ((counts[base + 1] + 7) & ~7) : 0;
    int v2 = (base + 2 < n) ? ((counts[base + 2] + 7) & ~7) : 0;
    int v3 = (base + 3 < n) ? ((counts[base + 3] + 7) & ~7) : 0;
    int tsum = v0 + v1 + v2 + v3;
    sd[tid] = tsum;
    __syncthreads();
    for (int off = 1; off < 256; off <<= 1) {
        int x = (tid >= off) ? sd[tid - off] : 0;
        __syncthreads();
        sd[tid] += x;
        __syncthreads();
    }
    if (tid == 255) blocksums[blockIdx.x] = sd[255];
    int run = sd[tid] - tsum;
    if (base + 0 < n) offsets[base + 0] = run;  run += v0;
    if (base + 1 < n) offsets[base + 1] = run;  run += v1;
    if (base + 2 < n) offsets[base + 2] = run;  run += v2;
    if (base + 3 < n) offsets[base + 3] = run;
}

__global__ __launch_bounds__(128) void scan2_k(int* __restrict__ blocksums, int nb) {
    __shared__ int sd[128];
    int tid = threadIdx.x;
    int v = (tid < nb) ? blocksums[tid] : 0;
    sd[tid] = v;
    __syncthreads();
    for (int off = 1; off < 128; off <<= 1) {
        int x = (tid >= off) ? sd[tid - off] : 0;
        __syncthreads();
        sd[tid] += x;
        __syncthreads();
    }
    if (tid < nb) blocksums[tid] = sd[tid] - v;  // exclusive
}

// finalize: padded offsets, dinv, pad records = sentinel row n.
__global__ void finalize_k(int* __restrict__ offsets,
                           float* __restrict__ dinv, const int* __restrict__ counts,
                           const int* __restrict__ blocksums,
                           int* __restrict__ el, int n) {
    int i = blockIdx.x * 256 + threadIdx.x;
    if (i >= n) return;
    int o = offsets[i] + blocksums[i >> 10];
    offsets[i] = o;
    int c = counts[i];
    dinv[i] = rsqrtf((float)(c + 1));  // +1 self-loop; deg>=1 always
    int cP = (c + 7) & ~7;
    for (int j = o + c; j < o + cP; ++j) el[j] = n;  // pad -> zero row
}

// scatter: atomic-free, 4-B records (src only).
__global__ __launch_bounds__(256) void scatter_k(const int* __restrict__ src,
                                                 const int* __restrict__ dst,
                                                 const int* __restrict__ rank,
                                                 const int* __restrict__ offsets,
                                                 int* __restrict__ el, int e) {
    int i0 = (blockIdx.x * 256 + threadIdx.x) * 4;
    if (i0 + 4 <= e) {
        int4 s4 = *(const int4*)(src + i0);
        int4 d4 = *(const int4*)(dst + i0);
        int4 r4 = *(const int4*)(rank + i0);
        el[offsets[d4.x] + r4.x] = s4.x;
        el[offsets[d4.y] + r4.y] = s4.y;
        el[offsets[d4.z] + r4.z] = s4.z;
        el[offsets[d4.w] + r4.w] = s4.w;
    } else {
        for (int i = i0; i < e; i++) el[offsets[dst[i]] + rank[i]] = src[i];
    }
}

// ---------------------------------------------------------------------------
// MFMA GEMM (layer 1): A fp32 split hi/lo bf16, W bf16 [n][k] in LDS.
// Output row scaled by dinv[row], packed bf16 -> pre-scaled gather table.
// ---------------------------------------------------------------------------
__global__ __launch_bounds__(256) void gemm_mfma_k(const float* __restrict__ A,
                                                   const unsigned* __restrict__ Wb,
                                                   const float* __restrict__ dinv,
                                                   unsigned* __restrict__ Cb, int M) {
    __shared__ ushort Bl[128 * 136];
    int tid = threadIdx.x;
    {
        unsigned* Bu = (unsigned*)Bl;
        for (int q = tid; q < 128 * 16; q += 256) {
            int row = q >> 4;
            int c = (q & 15) << 2;
            uint4 v = *(const uint4*)(Wb + (size_t)row * 64 + c);
            *(uint4*)(Bu + (size_t)row * 68 + c) = v;
        }
    }
    __syncthreads();

    int lane = tid & 63;
    int wv = tid >> 6;
    int quad = lane >> 4;
    int l15 = lane & 15;
    int r0 = blockIdx.x * 64 + wv * 16;
    int mload = r0 + l15;
    if (mload > M - 1) mload = M - 1;
    const float* Ar = A + (size_t)mload * 128 + quad * 8;

    float4v acc[8];
#pragma unroll
    for (int t = 0; t < 8; t++) acc[t] = (float4v){0.f, 0.f, 0.f, 0.f};

    for (int kp = 0; kp < 4; ++kp) {
        float4 a0 = *(const float4*)(Ar + kp * 32);
        float4 a1 = *(const float4*)(Ar + kp * 32 + 4);
        float af[8] = {a0.x, a0.y, a0.z, a0.w, a1.x, a1.y, a1.z, a1.w};
        short8 hi, lo;
#pragma unroll
        for (int j = 0; j < 8; j++) {
            unsigned h = bf16_rne(af[j]);
            hi[j] = (short)h;
            float res = af[j] - __uint_as_float(h << 16);
            lo[j] = (short)bf16_rne(res);
        }
        int kb = kp * 32 + quad * 8;
#pragma unroll
        for (int nt = 0; nt < 8; nt++) {
            short8 b8 = *(const short8*)(&Bl[(size_t)(nt * 16 + l15) * 136 + kb]);
            acc[nt] = __builtin_amdgcn_mfma_f32_16x16x32_bf16(hi, b8, acc[nt], 0, 0, 0);
            acc[nt] = __builtin_amdgcn_mfma_f32_16x16x32_bf16(lo, b8, acc[nt], 0, 0, 0);
        }
    }

    ushort* Cu = (ushort*)Cb;
#pragma unroll
    for (int r = 0; r < 4; r++) {
        int row = r0 + quad * 4 + r;
        if (row < M) {
            float dv = dinv[row];
#pragma unroll
            for (int nt = 0; nt < 8; nt++) {
                Cu[(size_t)row * 128 + nt * 16 + l15] =
                    (ushort)bf16_rne(acc[nt][r] * dv);
            }
        }
    }
}

// ---------------------------------------------------------------------------
// MFMA GEMM (layer 2): A already bf16 packed -> single mfma per tile.
// Output row scaled by dinv[row].
// ---------------------------------------------------------------------------
__global__ __launch_bounds__(256) void gemm_bf16_k(const unsigned* __restrict__ Ab,
                                                   const unsigned* __restrict__ Wb,
                                                   const float* __restrict__ dinv,
                                                   unsigned* __restrict__ Cb, int M) {
    __shared__ ushort Bl[128 * 136];
    int tid = threadIdx.x;
    {
        unsigned* Bu = (unsigned*)Bl;
        for (int q = tid; q < 128 * 16; q += 256) {
            int row = q >> 4;
            int c = (q & 15) << 2;
            uint4 v = *(const uint4*)(Wb + (size_t)row * 64 + c);
            *(uint4*)(Bu + (size_t)row * 68 + c) = v;
        }
    }
    __syncthreads();

    int lane = tid & 63;
    int wv = tid >> 6;
    int quad = lane >> 4;
    int l15 = lane & 15;
    int r0 = blockIdx.x * 64 + wv * 16;
    int mload = r0 + l15;
    if (mload > M - 1) mload = M - 1;
    const unsigned* Ar = Ab + (size_t)mload * 64 + quad * 4;

    float4v acc[8];
#pragma unroll
    for (int t = 0; t < 8; t++) acc[t] = (float4v){0.f, 0.f, 0.f, 0.f};

    for (int kp = 0; kp < 4; ++kp) {
        uint4 a4 = *(const uint4*)(Ar + kp * 16);
        short8 av;
        av[0] = (short)(a4.x & 0xffff); av[1] = (short)(a4.x >> 16);
        av[2] = (short)(a4.y & 0xffff); av[3] = (short)(a4.y >> 16);
        av[4] = (short)(a4.z & 0xffff); av[5] = (short)(a4.z >> 16);
        av[6] = (short)(a4.w & 0xffff); av[7] = (short)(a4.w >> 16);
        int kb = kp * 32 + quad * 8;
#pragma unroll
        for (int nt = 0; nt < 8; nt++) {
            short8 b8 = *(const short8*)(&Bl[(size_t)(nt * 16 + l15) * 136 + kb]);
            acc[nt] = __builtin_amdgcn_mfma_f32_16x16x32_bf16(av, b8, acc[nt], 0, 0, 0);
        }
    }

    ushort* Cu = (ushort*)Cb;
#pragma unroll
    for (int r = 0; r < 4; r++) {
        int row = r0 + quad * 4 + r;
        if (row < M) {
            float dv = dinv[row];
#pragma unroll
            for (int nt = 0; nt < 8; nt++) {
                Cu[(size_t)row * 128 + nt * 16 + l15] =
                    (ushort)bf16_rne(acc[nt][r] * dv);
            }
        }
    }
}

// ---------------------------------------------------------------------------
// Aggregation core: one wave per node; half-wave h takes edges [8g+4h, 8g+4h+4)
// of each 8-edge group via ONE broadcast int4; lane gathers uint2 (4 bf16
// feats). Pure adds (weights pre-folded into the table). Padded CSR.
// Returns UNSCALED sum incl. self row; caller multiplies by dinv[node].
// ---------------------------------------------------------------------------
__device__ __forceinline__ float4 agg_core(const uint2* __restrict__ Hu2,
                                           const int* __restrict__ el,
                                           int start, int cnt, int node,
                                           int li, int half) {
    float4 acc = make_float4(0.f, 0.f, 0.f, 0.f);
    int groups = ((cnt + 7) & ~7) >> 3;
    if (groups > 0) {
        const int* p = el + start + half * 4;
        int4 r = *(const int4*)p;
        for (int g = 0; g < groups; ++g) {
            uint2 g0 = Hu2[(size_t)r.x * 32 + li];
            uint2 g1 = Hu2[(size_t)r.y * 32 + li];
            uint2 g2 = Hu2[(size_t)r.z * 32 + li];
            uint2 g3 = Hu2[(size_t)r.w * 32 + li];
            int4 rn = *(const int4*)(p + 8 * (g + 1));  // tail-padded
            float2 f;
            f = unpack_bf2(g0.x); acc.x += f.x; acc.y += f.y;
            f = unpack_bf2(g0.y); acc.z += f.x; acc.w += f.y;
            f = unpack_bf2(g1.x); acc.x += f.x; acc.y += f.y;
            f = unpack_bf2(g1.y); acc.z += f.x; acc.w += f.y;
            f = unpack_bf2(g2.x); acc.x += f.x; acc.y += f.y;
            f = unpack_bf2(g2.y); acc.z += f.x; acc.w += f.y;
            f = unpack_bf2(g3.x); acc.x += f.x; acc.y += f.y;
            f = unpack_bf2(g3.y); acc.z += f.x; acc.w += f.y;
            r = rn;
        }
    }
    acc.x += __shfl_xor(acc.x, 32);
    acc.y += __shfl_xor(acc.y, 32);
    acc.z += __shfl_xor(acc.z, 32);
    acc.w += __shfl_xor(acc.w, 32);
    uint2 sv = Hu2[(size_t)node * 32 + li];  // self row (pre-scaled by dinv[node])
    float2 s0 = unpack_bf2(sv.x);
    float2 s1 = unpack_bf2(sv.y);
    acc.x += s0.x; acc.y += s0.y; acc.z += s1.x; acc.w += s1.y;
    return acc;
}

// Layer 1: *dinv, + b1, BN(eval), ReLU -> H1 packed bf16
__global__ __launch_bounds__(256) void agg1_k(
    const unsigned* __restrict__ H, const int* __restrict__ el,
    const int* __restrict__ offsets, const int* __restrict__ counts,
    const float* __restrict__ dinv, const float* __restrict__ b1,
    const float* __restrict__ gamma, const float* __restrict__ beta,
    const float* __restrict__ mean, const float* __restrict__ var,
    unsigned* __restrict__ H1b, int n) {
    int lane = threadIdx.x & 63;
    int li = lane & 31;
    int half = lane >> 5;
    int node = blockIdx.x * 4 + (threadIdx.x >> 6);
    if (node >= n) return;
    float4 acc = agg_core((const uint2*)H, el, offsets[node], counts[node],
                          node, li, half);
    if (half == 0) {
        float dv = dinv[node];
        int f0 = li * 4;
        float4 bb = *(const float4*)(b1 + f0);
        float4 mm = *(const float4*)(mean + f0);
        float4 vv = *(const float4*)(var + f0);
        float4 gg = *(const float4*)(gamma + f0);
        float4 be = *(const float4*)(beta + f0);
        float4 o;
        o.x = fmaxf((acc.x * dv + bb.x - mm.x) * rsqrtf(vv.x + BN_EPS) * gg.x + be.x, 0.f);
        o.y = fmaxf((acc.y * dv + bb.y - mm.y) * rsqrtf(vv.y + BN_EPS) * gg.y + be.y, 0.f);
        o.z = fmaxf((acc.z * dv + bb.z - mm.z) * rsqrtf(vv.z + BN_EPS) * gg.z + be.z, 0.f);
        o.w = fmaxf((acc.w * dv + bb.w - mm.w) * rsqrtf(vv.w + BN_EPS) * gg.w + be.w, 0.f);
        uint2 pk;
        pk.x = pack_bf2(o.x, o.y);
        pk.y = pack_bf2(o.z, o.w);
        *(uint2*)(H1b + (size_t)node * 64 + li * 2) = pk;
    }
}

// Layer 2: *dinv, + b2, then JK max with H1 (in-place bf16 H1 -> JK)
__global__ __launch_bounds__(256) void agg2_k(
    const unsigned* __restrict__ H, const int* __restrict__ el,
    const int* __restrict__ offsets, const int* __restrict__ counts,
    const float* __restrict__ dinv, const float* __restrict__ b2,
    unsigned* __restrict__ H1b, int n) {
    int lane = threadIdx.x & 63;
    int li = lane & 31;
    int half = lane >> 5;
    int node = blockIdx.x * 4 + (threadIdx.x >> 6);
    if (node >= n) return;
    float4 acc = agg_core((const uint2*)H, el, offsets[node], counts[node],
                          node, li, half);
    if (half == 0) {
        float dv = dinv[node];
        int f0 = li * 4;
        float4 bb = *(const float4*)(b2 + f0);
        uint2* p = (uint2*)(H1b + (size_t)node * 64 + li * 2);
        uint2 hv = *p;
        float2 ha = unpack_bf2(hv.x);
        float2 hb = unpack_bf2(hv.y);
        float4 o;
        o.x = fmaxf(ha.x, acc.x * dv + bb.x);
        o.y = fmaxf(ha.y, acc.y * dv + bb.y);
        o.z = fmaxf(hb.x, acc.z * dv + bb.z);
        o.w = fmaxf(hb.y, acc.w * dv + bb.w);
        uint2 pk;
        pk.x = pack_bf2(o.x, o.y);
        pk.y = pack_bf2(o.z, o.w);
        *p = pk;
    }
}

// ---------------------------------------------------------------------------
// Head: tiled GEMM (64 nodes x 48 cols, K=128) + fused log_softmax.
// JK input is packed bf16 [n][64 uints].
// ---------------------------------------------------------------------------
__global__ __launch_bounds__(256) void head_k(const unsigned* __restrict__ JKb,
                                              const float* __restrict__ Wf,
                                              const float* __restrict__ bf,
                                              float* __restrict__ out, int n) {
    __shared__ __align__(16) float Bs[48 * 132];  // [col][k], stride 132
    __shared__ __align__(16) float As[64 * 36];   // [row][k-in-panel], stride 36
    int tid = threadIdx.x;
    for (int p = tid; p < 47 * 32; p += 256) {
        int c = p >> 5;          // 0..46
        int k0 = (p & 31) << 2;  // 0,4,...,124
        float4 v;
        v.x = Wf[(size_t)(k0 + 0) * DOUT + c];
        v.y = Wf[(size_t)(k0 + 1) * DOUT + c];
        v.z = Wf[(size_t)(k0 + 2) * DOUT + c];
        v.w = Wf[(size_t)(k0 + 3) * DOUT + c];
        *(float4*)(&Bs[c * 132 + k0]) = v;
    }
    int tx = tid & 15;   // col group: cols [3*tx, 3*tx+3)
    int ty = tid >> 4;   // row group: rows [4*ty, 4*ty+4)
    int node0 = blockIdx.x * 64;

    float acc[4][3];
#pragma unroll
    for (int i = 0; i < 4; i++)
#pragma unroll
        for (int j = 0; j < 3; j++) acc[i][j] = 0.f;

    for (int kk = 0; kk < 128; kk += 32) {
        __syncthreads();
        for (int l = tid; l < 512; l += 256) {
            int r = l >> 3;
            int c4 = (l & 7) << 2;
            int row = node0 + r;
            float4 v = make_float4(0.f, 0.f, 0.f, 0.f);
            if (row < n) {
                uint2 u = *(const uint2*)(JKb + (size_t)row * 64 + ((kk + c4) >> 1));
                float2 f0 = unpack_bf2(u.x);
                float2 f1 = unpack_bf2(u.y);
                v = make_float4(f0.x, f0.y, f1.x, f1.y);
            }
            *(float4*)(&As[r * 36 + c4]) = v;
        }
        __syncthreads();
#pragma unroll
        for (int k4 = 0; k4 < 32; k4 += 4) {
            float4 a0 = *(const float4*)(&As[(ty * 4 + 0) * 36 + k4]);
            float4 a1 = *(const float4*)(&As[(ty * 4 + 1) * 36 + k4]);
            float4 a2 = *(const float4*)(&As[(ty * 4 + 2) * 36 + k4]);
            float4 a3 = *(const float4*)(&As[(ty * 4 + 3) * 36 + k4]);
            float4 b0 = *(const float4*)(&Bs[(tx * 3 + 0) * 132 + kk + k4]);
            float4 b1 = *(const float4*)(&Bs[(tx * 3 + 1) * 132 + kk + k4]);
            float4 b2 = *(const float4*)(&Bs[(tx * 3 + 2) * 132 + kk + k4]);
#define DOT_ROW(i, a)                                                        \
            acc[i][0] = fmaf(a.x, b0.x, acc[i][0]);                          \
            acc[i][0] = fmaf(a.y, b0.y, acc[i][0]);                          \
            acc[i][0] = fmaf(a.z, b0.z, acc[i][0]);                          \
            acc[i][0] = fmaf(a.w, b0.w, acc[i][0]);                          \
            acc[i][1] = fmaf(a.x, b1.x, acc[i][1]);                          \
            acc[i][1] = fmaf(a.y, b1.y, acc[i][1]);                          \
            acc[i][1] = fmaf(a.z, b1.z, acc[i][1]);                          \
            acc[i][1] = fmaf(a.w, b1.w, acc[i][1]);                          \
            acc[i][2] = fmaf(a.x, b2.x, acc[i][2]);                          \
            acc[i][2] = fmaf(a.y, b2.y, acc[i][2]);                          \
            acc[i][2] = fmaf(a.z, b2.z, acc[i][2]);                          \
            acc[i][2] = fmaf(a.w, b2.w, acc[i][2]);
            DOT_ROW(0, a0)
            DOT_ROW(1, a1)
            DOT_ROW(2, a2)
            DOT_ROW(3, a3)
#undef DOT_ROW
        }
    }

    float bfv[3];
#pragma unroll
    for (int j = 0; j < 3; j++) {
        int c = tx * 3 + j;
        bfv[j] = (c < DOUT) ? bf[c] : 0.f;
    }
#pragma unroll
    for (int i = 0; i < 4; i++) {
        int node = node0 + ty * 4 + i;
        float l0 = acc[i][0] + bfv[0];
        float l1 = acc[i][1] + bfv[1];
        float l2 = acc[i][2] + bfv[2];
        bool v2ok = (tx * 3 + 2) < DOUT;  // only col 47 (tx=15,j=2) invalid
        float m = fmaxf(l0, l1);
        if (v2ok) m = fmaxf(m, l2);
        for (int off = 8; off >= 1; off >>= 1) m = fmaxf(m, __shfl_xor(m, off));
        float s = expf(l0 - m) + expf(l1 - m) + (v2ok ? expf(l2 - m) : 0.f);
        for (int off = 8; off >= 1; off >>= 1) s += __shfl_xor(s, off);
        float ls = m + logf(s);
        if (node < n) {
            float* o = out + (size_t)node * DOUT + tx * 3;
            o[0] = l0 - ls;
            o[1] = l1 - ls;
            if (v2ok) o[2] = l2 - ls;
        }
    }
}

// ---------------------------------------------------------------------------
extern "C" void kernel_launch(void* const* d_in, const int* in_sizes, int n_in,
                              void* d_out, int out_size, void* d_ws, size_t ws_size,
                              hipStream_t stream) {
    const float* x     = (const float*)d_in[0];
    const int*   ei    = (const int*)d_in[1];
    const float* W1    = (const float*)d_in[2];
    const float* b1    = (const float*)d_in[3];
    const float* gamma = (const float*)d_in[4];
    const float* beta  = (const float*)d_in[5];
    const float* mean  = (const float*)d_in[6];
    const float* var   = (const float*)d_in[7];
    const float* W2    = (const float*)d_in[8];
    const float* b2    = (const float*)d_in[9];
    const float* Wf    = (const float*)d_in[10];
    const float* bf    = (const float*)d_in[11];
    float* out = (float*)d_out;

    int N_ = in_sizes[0] / 128;
    int E_ = in_sizes[1] / 2;
    const int* src = ei;
    const int* dst = ei + E_;

    char* ws = (char*)d_ws;
    unsigned* bufA = (unsigned*)ws; ws += (size_t)(N_ + 1) * 64 * 4;  // bf16 table + sentinel row
    unsigned* h1b  = (unsigned*)ws; ws += (size_t)N_ * 64 * 4;        // bf16 h1 / JK
    int*   counts  = (int*)ws;    ws += (size_t)N_ * 4;
    int*   offsets = (int*)ws;    ws += (size_t)N_ * 4;
    float* dinv    = (float*)ws;  ws += (size_t)N_ * 4;
    int*   rank    = (int*)ws;    ws += (size_t)E_ * 4;
    // padded edge list (4-B src indices): sum((c+7)&~7) <= E+7N; +16 tail pad
    int*   el      = (int*)ws;    ws += ((size_t)E_ + 7 * (size_t)N_ + 16) * 4;
    int*   bsums   = (int*)ws;    ws += 1024 * 4;
    unsigned* W1b  = (unsigned*)ws; ws += 128 * 64 * 4;               // bf16 W^T [n][k]
    unsigned* W2b  = (unsigned*)ws; ws += 128 * 64 * 4;

    int nb = (N_ + 1023) / 1024;
    int gemmBlocks = (N_ + 63) / 64;
    int edgeBlocks = (E_ + 1023) / 1024;  // 4 edges/thread

    prep_k<<<2 + (N_ + 255) / 256, 256, 0, stream>>>(W1, W2, W1b, W2b,
                                                     counts, bufA, N_);
    count_rank_k<<<edgeBlocks, 256, 0, stream>>>(dst, counts, rank, E_);
    scan1_k<<<nb, 256, 0, stream>>>(counts, offsets, bsums, N_);
    scan2_k<<<1, 128, 0, stream>>>(bsums, nb);
    finalize_k<<<(N_ + 255) / 256, 256, 0, stream>>>(offsets, dinv,
                                                     counts, bsums, el, N_);
    scatter_k<<<edgeBlocks, 256, 0, stream>>>(src, dst, rank, offsets, el, E_);

    // layer 1 (pre-scaled table)
    gemm_mfma_k<<<gemmBlocks, 256, 0, stream>>>(x, W1b, dinv, bufA, N_);
    agg1_k<<<(N_ + 3) / 4, 256, 0, stream>>>(bufA, el, offsets, counts, dinv,
                                             b1, gamma, beta, mean, var, h1b, N_);
    // layer 2 (bf16 A -> single-mfma gemm, pre-scaled table)
    gemm_bf16_k<<<gemmBlocks, 256, 0, stream>>>(h1b, W2b, dinv, bufA, N_);
    agg2_k<<<(N_ + 3) / 4, 256, 0, stream>>>(bufA, el, offsets, counts, dinv,
                                             b2, h1b, N_);
    // head: h1b now holds jk = max(h1, h2) in bf16; 64 nodes per block
    head_k<<<(N_ + 63) / 64, 256, 0, stream>>>(h1b, Wf, bf, out, N_);
}

// Round 15
// 417.152 us; speedup vs baseline: 1.3863x; 1.0187x over previous
//
#include <hip/hip_runtime.h>
#include <math.h>

// Problem constants (from reference): N=100000, E=1600000, D_IN=D_H=128, D_OUT=47
#define DH 128
#define DOUT 47
#define BN_EPS 1e-5f

typedef __attribute__((ext_vector_type(8))) short short8;
typedef __attribute__((ext_vector_type(4))) float float4v;

// ---------------------------------------------------------------------------
// bf16 pack/unpack (RNE).
// ---------------------------------------------------------------------------
__device__ __forceinline__ unsigned bf16_rne(float f) {
    unsigned u = __float_as_uint(f);
    return (u + 0x7fffu + ((u >> 16) & 1u)) >> 16;
}
__device__ __forceinline__ unsigned pack_bf2(float a, float b) {
    return (bf16_rne(a) & 0xffffu) | (bf16_rne(b) << 16);
}
__device__ __forceinline__ float2 unpack_bf2(unsigned u) {
    return make_float2(__uint_as_float(u << 16),
                       __uint_as_float(u & 0xffff0000u));
}

// ---------------------------------------------------------------------------
// Pre-scaled-table GCN: table row g[s] = dinv[s] * (X@W)[s]; edge record is a
// bare 4-B src index; pads/tail point at zeroed sentinel row N.
// ---------------------------------------------------------------------------

// prep: block 0 -> W1 transpose+bf16 (+ zero sentinel row of bufA),
//       block 1 -> W2, blocks >=2 -> zero counts.
__global__ __launch_bounds__(256) void prep_k(const float* __restrict__ W1,
                                              const float* __restrict__ W2,
                                              unsigned* __restrict__ W1b,
                                              unsigned* __restrict__ W2b,
                                              int* __restrict__ counts,
                                              unsigned* __restrict__ bufA, int n) {
    int tid = threadIdx.x;
    if (blockIdx.x >= 2) {
        int i = (blockIdx.x - 2) * 256 + tid;
        if (i < n) counts[i] = 0;
        return;
    }
    const float* W = blockIdx.x ? W2 : W1;
    unsigned* Wb = blockIdx.x ? W2b : W1b;
    if (blockIdx.x == 0 && tid < 64) bufA[(size_t)n * 64 + tid] = 0;  // sentinel row
    for (int p = tid; p < 128 * 32; p += 256) {
        int nn = p >> 5;
        int k0 = (p & 31) << 2;
        float f0 = W[(size_t)(k0 + 0) * 128 + nn];
        float f1 = W[(size_t)(k0 + 1) * 128 + nn];
        float f2 = W[(size_t)(k0 + 2) * 128 + nn];
        float f3 = W[(size_t)(k0 + 3) * 128 + nn];
        uint2 v;
        v.x = pack_bf2(f0, f1);
        v.y = pack_bf2(f2, f3);
        *(uint2*)(Wb + (size_t)nn * 64 + (k0 >> 1)) = v;
    }
}

__global__ __launch_bounds__(256) void count_rank_k(const int* __restrict__ dst,
                                                    int* __restrict__ counts,
                                                    int* __restrict__ rank, int e) {
    int i0 = (blockIdx.x * 256 + threadIdx.x) * 4;
    if (i0 + 4 <= e) {
        int4 d4 = *(const int4*)(dst + i0);
        int4 r4;
        r4.x = atomicAdd(&counts[d4.x], 1);
        r4.y = atomicAdd(&counts[d4.y], 1);
        r4.z = atomicAdd(&counts[d4.z], 1);
        r4.w = atomicAdd(&counts[d4.w], 1);
        *(int4*)(rank + i0) = r4;
    } else {
        for (int i = i0; i < e; i++) rank[i] = atomicAdd(&counts[dst[i]], 1);
    }
}

// scan1 scans PADDED counts ((c+7)&~7).
__global__ __launch_bounds__(256) void scan1_k(const int* __restrict__ counts,
                                               int* __restrict__ offsets,
                                               int* __restrict__ blocksums, int n) {
    __shared__ int sd[256];
    int tid = threadIdx.x;
    int base = blockIdx.x * 1024 + tid * 4;
    int v0 = (base + 0 < n) ? ((counts[base + 0] + 7) & ~7) : 0;
    int v1 = (base + 1 < n) ? ((counts[base + 1] + 7) & ~7) : 0;
    int v2 = (base + 2 < n) ? ((counts[base + 2] + 7) & ~7) : 0;
    int v3 = (base + 3 < n) ? ((counts[base + 3] + 7) & ~7) : 0;
    int tsum = v0 + v1 + v2 + v3;
    sd[tid] = tsum;
    __syncthreads();
    for (int off = 1; off < 256; off <<= 1) {
        int x = (tid >= off) ? sd[tid - off] : 0;
        __syncthreads();
        sd[tid] += x;
        __syncthreads();
    }
    if (tid == 255) blocksums[blockIdx.x] = sd[255];
    int run = sd[tid] - tsum;
    if (base + 0 < n) offsets[base + 0] = run;  run += v0;
    if (base + 1 < n) offsets[base + 1] = run;  run += v1;
    if (base + 2 < n) offsets[base + 2] = run;  run += v2;
    if (base + 3 < n) offsets[base + 3] = run;
}

// scan2: exclusive scan of block sums + write el tail sentinels (row n) so
// the agg pipeline's phantom prefetches always read valid row indices.
__global__ __launch_bounds__(128) void scan2_k(int* __restrict__ blocksums, int nb,
                                               int* __restrict__ el, int n) {
    __shared__ int sd[128];
    int tid = threadIdx.x;
    int v = (tid < nb) ? blocksums[tid] : 0;
    sd[tid] = v;
    __syncthreads();
    for (int off = 1; off < 128; off <<= 1) {
        int x = (tid >= off) ? sd[tid - off] : 0;
        __syncthreads();
        sd[tid] += x;
        __syncthreads();
    }
    if (tid < nb) blocksums[tid] = sd[tid] - v;  // exclusive
    int total = sd[127];                         // total padded edges
    if (tid < 96) el[total + tid] = n;           // sentinel tail
}

// finalize: padded offsets, dinv, pad records = sentinel row n.
__global__ void finalize_k(int* __restrict__ offsets,
                           float* __restrict__ dinv, const int* __restrict__ counts,
                           const int* __restrict__ blocksums,
                           int* __restrict__ el, int n) {
    int i = blockIdx.x * 256 + threadIdx.x;
    if (i >= n) return;
    int o = offsets[i] + blocksums[i >> 10];
    offsets[i] = o;
    int c = counts[i];
    dinv[i] = rsqrtf((float)(c + 1));  // +1 self-loop; deg>=1 always
    int cP = (c + 7) & ~7;
    for (int j = o + c; j < o + cP; ++j) el[j] = n;  // pad -> zero row
}

// scatter: atomic-free, 4-B records (src only).
__global__ __launch_bounds__(256) void scatter_k(const int* __restrict__ src,
                                                 const int* __restrict__ dst,
                                                 const int* __restrict__ rank,
                                                 const int* __restrict__ offsets,
                                                 int* __restrict__ el, int e) {
    int i0 = (blockIdx.x * 256 + threadIdx.x) * 4;
    if (i0 + 4 <= e) {
        int4 s4 = *(const int4*)(src + i0);
        int4 d4 = *(const int4*)(dst + i0);
        int4 r4 = *(const int4*)(rank + i0);
        el[offsets[d4.x] + r4.x] = s4.x;
        el[offsets[d4.y] + r4.y] = s4.y;
        el[offsets[d4.z] + r4.z] = s4.z;
        el[offsets[d4.w] + r4.w] = s4.w;
    } else {
        for (int i = i0; i < e; i++) el[offsets[dst[i]] + rank[i]] = src[i];
    }
}

// ---------------------------------------------------------------------------
// MFMA GEMM (layer 1): A fp32 -> bf16 in-register (single mfma per tile;
// x-quantization is the same error class as the accepted bf16 roundings),
// W bf16 [n][k] in LDS. Output row scaled by dinv[row], packed bf16.
// ---------------------------------------------------------------------------
__global__ __launch_bounds__(256) void gemm_mfma_k(const float* __restrict__ A,
                                                   const unsigned* __restrict__ Wb,
                                                   const float* __restrict__ dinv,
                                                   unsigned* __restrict__ Cb, int M) {
    __shared__ ushort Bl[128 * 136];
    int tid = threadIdx.x;
    {
        unsigned* Bu = (unsigned*)Bl;
        for (int q = tid; q < 128 * 16; q += 256) {
            int row = q >> 4;
            int c = (q & 15) << 2;
            uint4 v = *(const uint4*)(Wb + (size_t)row * 64 + c);
            *(uint4*)(Bu + (size_t)row * 68 + c) = v;
        }
    }
    __syncthreads();

    int lane = tid & 63;
    int wv = tid >> 6;
    int quad = lane >> 4;
    int l15 = lane & 15;
    int r0 = blockIdx.x * 64 + wv * 16;
    int mload = r0 + l15;
    if (mload > M - 1) mload = M - 1;
    const float* Ar = A + (size_t)mload * 128 + quad * 8;

    float4v acc[8];
#pragma unroll
    for (int t = 0; t < 8; t++) acc[t] = (float4v){0.f, 0.f, 0.f, 0.f};

    for (int kp = 0; kp < 4; ++kp) {
        float4 a0 = *(const float4*)(Ar + kp * 32);
        float4 a1 = *(const float4*)(Ar + kp * 32 + 4);
        float af[8] = {a0.x, a0.y, a0.z, a0.w, a1.x, a1.y, a1.z, a1.w};
        short8 av;
#pragma unroll
        for (int j = 0; j < 8; j++) av[j] = (short)bf16_rne(af[j]);
        int kb = kp * 32 + quad * 8;
#pragma unroll
        for (int nt = 0; nt < 8; nt++) {
            short8 b8 = *(const short8*)(&Bl[(size_t)(nt * 16 + l15) * 136 + kb]);
            acc[nt] = __builtin_amdgcn_mfma_f32_16x16x32_bf16(av, b8, acc[nt], 0, 0, 0);
        }
    }

    ushort* Cu = (ushort*)Cb;
#pragma unroll
    for (int r = 0; r < 4; r++) {
        int row = r0 + quad * 4 + r;
        if (row < M) {
            float dv = dinv[row];
#pragma unroll
            for (int nt = 0; nt < 8; nt++) {
                Cu[(size_t)row * 128 + nt * 16 + l15] =
                    (ushort)bf16_rne(acc[nt][r] * dv);
            }
        }
    }
}

// ---------------------------------------------------------------------------
// MFMA GEMM (layer 2): A already bf16 packed -> single mfma per tile.
// Output row scaled by dinv[row].
// ---------------------------------------------------------------------------
__global__ __launch_bounds__(256) void gemm_bf16_k(const unsigned* __restrict__ Ab,
                                                   const unsigned* __restrict__ Wb,
                                                   const float* __restrict__ dinv,
                                                   unsigned* __restrict__ Cb, int M) {
    __shared__ ushort Bl[128 * 136];
    int tid = threadIdx.x;
    {
        unsigned* Bu = (unsigned*)Bl;
        for (int q = tid; q < 128 * 16; q += 256) {
            int row = q >> 4;
            int c = (q & 15) << 2;
            uint4 v = *(const uint4*)(Wb + (size_t)row * 64 + c);
            *(uint4*)(Bu + (size_t)row * 68 + c) = v;
        }
    }
    __syncthreads();

    int lane = tid & 63;
    int wv = tid >> 6;
    int quad = lane >> 4;
    int l15 = lane & 15;
    int r0 = blockIdx.x * 64 + wv * 16;
    int mload = r0 + l15;
    if (mload > M - 1) mload = M - 1;
    const unsigned* Ar = Ab + (size_t)mload * 64 + quad * 4;

    float4v acc[8];
#pragma unroll
    for (int t = 0; t < 8; t++) acc[t] = (float4v){0.f, 0.f, 0.f, 0.f};

    for (int kp = 0; kp < 4; ++kp) {
        uint4 a4 = *(const uint4*)(Ar + kp * 16);
        short8 av;
        av[0] = (short)(a4.x & 0xffff); av[1] = (short)(a4.x >> 16);
        av[2] = (short)(a4.y & 0xffff); av[3] = (short)(a4.y >> 16);
        av[4] = (short)(a4.z & 0xffff); av[5] = (short)(a4.z >> 16);
        av[6] = (short)(a4.w & 0xffff); av[7] = (short)(a4.w >> 16);
        int kb = kp * 32 + quad * 8;
#pragma unroll
        for (int nt = 0; nt < 8; nt++) {
            short8 b8 = *(const short8*)(&Bl[(size_t)(nt * 16 + l15) * 136 + kb]);
            acc[nt] = __builtin_amdgcn_mfma_f32_16x16x32_bf16(av, b8, acc[nt], 0, 0, 0);
        }
    }

    ushort* Cu = (ushort*)Cb;
#pragma unroll
    for (int r = 0; r < 4; r++) {
        int row = r0 + quad * 4 + r;
        if (row < M) {
            float dv = dinv[row];
#pragma unroll
            for (int nt = 0; nt < 8; nt++) {
                Cu[(size_t)row * 128 + nt * 16 + l15] =
                    (ushort)bf16_rne(acc[nt][r] * dv);
            }
        }
    }
}

// ---------------------------------------------------------------------------
// Aggregation core v5: 2-deep software pipeline. Half-wave h takes edges
// [8g+4h, 8g+4h+4) of each 8-edge group via one broadcast int4; lane gathers
// uint2 (4 bf16 feats). While accumulating group g, group g+1's features and
// group g+2's recs are in flight (8 gathers/half-wave outstanding). Phantom
// prefetches read the next node's list or the sentinel tail (always valid).
// Returns UNSCALED sum incl. self row; caller multiplies by dinv[node].
// ---------------------------------------------------------------------------
__device__ __forceinline__ float4 agg_core(const uint2* __restrict__ Hu2,
                                           const int* __restrict__ el,
                                           int start, int cnt, int node,
                                           int li, int half) {
    float4 acc = make_float4(0.f, 0.f, 0.f, 0.f);
    int groups = ((cnt + 7) & ~7) >> 3;
    if (groups > 0) {
        const int* p = el + start + half * 4;
        int4 r = *(const int4*)p;
        uint2 c0 = Hu2[(size_t)r.x * 32 + li];
        uint2 c1 = Hu2[(size_t)r.y * 32 + li];
        uint2 c2 = Hu2[(size_t)r.z * 32 + li];
        uint2 c3 = Hu2[(size_t)r.w * 32 + li];
        int4 rn = *(const int4*)(p + 8);
        for (int g = 0; g < groups; ++g) {
            // in-flight: features for group g+1
            uint2 n0 = Hu2[(size_t)rn.x * 32 + li];
            uint2 n1 = Hu2[(size_t)rn.y * 32 + li];
            uint2 n2 = Hu2[(size_t)rn.z * 32 + li];
            uint2 n3 = Hu2[(size_t)rn.w * 32 + li];
            // recs for group g+2
            int4 r2 = *(const int4*)(p + 8 * (g + 2));
            // accumulate group g
            float2 f;
            f = unpack_bf2(c0.x); acc.x += f.x; acc.y += f.y;
            f = unpack_bf2(c0.y); acc.z += f.x; acc.w += f.y;
            f = unpack_bf2(c1.x); acc.x += f.x; acc.y += f.y;
            f = unpack_bf2(c1.y); acc.z += f.x; acc.w += f.y;
            f = unpack_bf2(c2.x); acc.x += f.x; acc.y += f.y;
            f = unpack_bf2(c2.y); acc.z += f.x; acc.w += f.y;
            f = unpack_bf2(c3.x); acc.x += f.x; acc.y += f.y;
            f = unpack_bf2(c3.y); acc.z += f.x; acc.w += f.y;
            c0 = n0; c1 = n1; c2 = n2; c3 = n3;
            rn = r2;
        }
    }
    acc.x += __shfl_xor(acc.x, 32);
    acc.y += __shfl_xor(acc.y, 32);
    acc.z += __shfl_xor(acc.z, 32);
    acc.w += __shfl_xor(acc.w, 32);
    uint2 sv = Hu2[(size_t)node * 32 + li];  // self row (pre-scaled by dinv[node])
    float2 s0 = unpack_bf2(sv.x);
    float2 s1 = unpack_bf2(sv.y);
    acc.x += s0.x; acc.y += s0.y; acc.z += s1.x; acc.w += s1.y;
    return acc;
}

// Layer 1: *dinv, + b1, BN(eval), ReLU -> H1 packed bf16
__global__ __launch_bounds__(256) void agg1_k(
    const unsigned* __restrict__ H, const int* __restrict__ el,
    const int* __restrict__ offsets, const int* __restrict__ counts,
    const float* __restrict__ dinv, const float* __restrict__ b1,
    const float* __restrict__ gamma, const float* __restrict__ beta,
    const float* __restrict__ mean, const float* __restrict__ var,
    unsigned* __restrict__ H1b, int n) {
    int lane = threadIdx.x & 63;
    int li = lane & 31;
    int half = lane >> 5;
    int node = blockIdx.x * 4 + (threadIdx.x >> 6);
    if (node >= n) return;
    float4 acc = agg_core((const uint2*)H, el, offsets[node], counts[node],
                          node, li, half);
    if (half == 0) {
        float dv = dinv[node];
        int f0 = li * 4;
        float4 bb = *(const float4*)(b1 + f0);
        float4 mm = *(const float4*)(mean + f0);
        float4 vv = *(const float4*)(var + f0);
        float4 gg = *(const float4*)(gamma + f0);
        float4 be = *(const float4*)(beta + f0);
        float4 o;
        o.x = fmaxf((acc.x * dv + bb.x - mm.x) * rsqrtf(vv.x + BN_EPS) * gg.x + be.x, 0.f);
        o.y = fmaxf((acc.y * dv + bb.y - mm.y) * rsqrtf(vv.y + BN_EPS) * gg.y + be.y, 0.f);
        o.z = fmaxf((acc.z * dv + bb.z - mm.z) * rsqrtf(vv.z + BN_EPS) * gg.z + be.z, 0.f);
        o.w = fmaxf((acc.w * dv + bb.w - mm.w) * rsqrtf(vv.w + BN_EPS) * gg.w + be.w, 0.f);
        uint2 pk;
        pk.x = pack_bf2(o.x, o.y);
        pk.y = pack_bf2(o.z, o.w);
        *(uint2*)(H1b + (size_t)node * 64 + li * 2) = pk;
    }
}

// Layer 2: *dinv, + b2, then JK max with H1 (in-place bf16 H1 -> JK)
__global__ __launch_bounds__(256) void agg2_k(
    const unsigned* __restrict__ H, const int* __restrict__ el,
    const int* __restrict__ offsets, const int* __restrict__ counts,
    const float* __restrict__ dinv, const float* __restrict__ b2,
    unsigned* __restrict__ H1b, int n) {
    int lane = threadIdx.x & 63;
    int li = lane & 31;
    int half = lane >> 5;
    int node = blockIdx.x * 4 + (threadIdx.x >> 6);
    if (node >= n) return;
    float4 acc = agg_core((const uint2*)H, el, offsets[node], counts[node],
                          node, li, half);
    if (half == 0) {
        float dv = dinv[node];
        int f0 = li * 4;
        float4 bb = *(const float4*)(b2 + f0);
        uint2* p = (uint2*)(H1b + (size_t)node * 64 + li * 2);
        uint2 hv = *p;
        float2 ha = unpack_bf2(hv.x);
        float2 hb = unpack_bf2(hv.y);
        float4 o;
        o.x = fmaxf(ha.x, acc.x * dv + bb.x);
        o.y = fmaxf(ha.y, acc.y * dv + bb.y);
        o.z = fmaxf(hb.x, acc.z * dv + bb.z);
        o.w = fmaxf(hb.y, acc.w * dv + bb.w);
        uint2 pk;
        pk.x = pack_bf2(o.x, o.y);
        pk.y = pack_bf2(o.z, o.w);
        *p = pk;
    }
}

// ---------------------------------------------------------------------------
// Head: tiled GEMM (64 nodes x 48 cols, K=128) + fused log_softmax.
// JK input is packed bf16 [n][64 uints].
// ---------------------------------------------------------------------------
__global__ __launch_bounds__(256) void head_k(const unsigned* __restrict__ JKb,
                                              const float* __restrict__ Wf,
                                              const float* __restrict__ bf,
                                              float* __restrict__ out, int n) {
    __shared__ __align__(16) float Bs[48 * 132];  // [col][k], stride 132
    __shared__ __align__(16) float As[64 * 36];   // [row][k-in-panel], stride 36
    int tid = threadIdx.x;
    for (int p = tid; p < 47 * 32; p += 256) {
        int c = p >> 5;          // 0..46
        int k0 = (p & 31) << 2;  // 0,4,...,124
        float4 v;
        v.x = Wf[(size_t)(k0 + 0) * DOUT + c];
        v.y = Wf[(size_t)(k0 + 1) * DOUT + c];
        v.z = Wf[(size_t)(k0 + 2) * DOUT + c];
        v.w = Wf[(size_t)(k0 + 3) * DOUT + c];
        *(float4*)(&Bs[c * 132 + k0]) = v;
    }
    int tx = tid & 15;   // col group: cols [3*tx, 3*tx+3)
    int ty = tid >> 4;   // row group: rows [4*ty, 4*ty+4)
    int node0 = blockIdx.x * 64;

    float acc[4][3];
#pragma unroll
    for (int i = 0; i < 4; i++)
#pragma unroll
        for (int j = 0; j < 3; j++) acc[i][j] = 0.f;

    for (int kk = 0; kk < 128; kk += 32) {
        __syncthreads();
        for (int l = tid; l < 512; l += 256) {
            int r = l >> 3;
            int c4 = (l & 7) << 2;
            int row = node0 + r;
            float4 v = make_float4(0.f, 0.f, 0.f, 0.f);
            if (row < n) {
                uint2 u = *(const uint2*)(JKb + (size_t)row * 64 + ((kk + c4) >> 1));
                float2 f0 = unpack_bf2(u.x);
                float2 f1 = unpack_bf2(u.y);
                v = make_float4(f0.x, f0.y, f1.x, f1.y);
            }
            *(float4*)(&As[r * 36 + c4]) = v;
        }
        __syncthreads();
#pragma unroll
        for (int k4 = 0; k4 < 32; k4 += 4) {
            float4 a0 = *(const float4*)(&As[(ty * 4 + 0) * 36 + k4]);
            float4 a1 = *(const float4*)(&As[(ty * 4 + 1) * 36 + k4]);
            float4 a2 = *(const float4*)(&As[(ty * 4 + 2) * 36 + k4]);
            float4 a3 = *(const float4*)(&As[(ty * 4 + 3) * 36 + k4]);
            float4 b0 = *(const float4*)(&Bs[(tx * 3 + 0) * 132 + kk + k4]);
            float4 b1 = *(const float4*)(&Bs[(tx * 3 + 1) * 132 + kk + k4]);
            float4 b2 = *(const float4*)(&Bs[(tx * 3 + 2) * 132 + kk + k4]);
#define DOT_ROW(i, a)                                                        \
            acc[i][0] = fmaf(a.x, b0.x, acc[i][0]);                          \
            acc[i][0] = fmaf(a.y, b0.y, acc[i][0]);                          \
            acc[i][0] = fmaf(a.z, b0.z, acc[i][0]);                          \
            acc[i][0] = fmaf(a.w, b0.w, acc[i][0]);                          \
            acc[i][1] = fmaf(a.x, b1.x, acc[i][1]);                          \
            acc[i][1] = fmaf(a.y, b1.y, acc[i][1]);                          \
            acc[i][1] = fmaf(a.z, b1.z, acc[i][1]);                          \
            acc[i][1] = fmaf(a.w, b1.w, acc[i][1]);                          \
            acc[i][2] = fmaf(a.x, b2.x, acc[i][2]);                          \
            acc[i][2] = fmaf(a.y, b2.y, acc[i][2]);                          \
            acc[i][2] = fmaf(a.z, b2.z, acc[i][2]);                          \
            acc[i][2] = fmaf(a.w, b2.w, acc[i][2]);
            DOT_ROW(0, a0)
            DOT_ROW(1, a1)
            DOT_ROW(2, a2)
            DOT_ROW(3, a3)
#undef DOT_ROW
        }
    }

    float bfv[3];
#pragma unroll
    for (int j = 0; j < 3; j++) {
        int c = tx * 3 + j;
        bfv[j] = (c < DOUT) ? bf[c] : 0.f;
    }
#pragma unroll
    for (int i = 0; i < 4; i++) {
        int node = node0 + ty * 4 + i;
        float l0 = acc[i][0] + bfv[0];
        float l1 = acc[i][1] + bfv[1];
        float l2 = acc[i][2] + bfv[2];
        bool v2ok = (tx * 3 + 2) < DOUT;  // only col 47 (tx=15,j=2) invalid
        float m = fmaxf(l0, l1);
        if (v2ok) m = fmaxf(m, l2);
        for (int off = 8; off >= 1; off >>= 1) m = fmaxf(m, __shfl_xor(m, off));
        float s = expf(l0 - m) + expf(l1 - m) + (v2ok ? expf(l2 - m) : 0.f);
        for (int off = 8; off >= 1; off >>= 1) s += __shfl_xor(s, off);
        float ls = m + logf(s);
        if (node < n) {
            float* o = out + (size_t)node * DOUT + tx * 3;
            o[0] = l0 - ls;
            o[1] = l1 - ls;
            if (v2ok) o[2] = l2 - ls;
        }
    }
}

// ---------------------------------------------------------------------------
extern "C" void kernel_launch(void* const* d_in, const int* in_sizes, int n_in,
                              void* d_out, int out_size, void* d_ws, size_t ws_size,
                              hipStream_t stream) {
    const float* x     = (const float*)d_in[0];
    const int*   ei    = (const int*)d_in[1];
    const float* W1    = (const float*)d_in[2];
    const float* b1    = (const float*)d_in[3];
    const float* gamma = (const float*)d_in[4];
    const float* beta  = (const float*)d_in[5];
    const float* mean  = (const float*)d_in[6];
    const float* var   = (const float*)d_in[7];
    const float* W2    = (const float*)d_in[8];
    const float* b2    = (const float*)d_in[9];
    const float* Wf    = (const float*)d_in[10];
    const float* bf    = (const float*)d_in[11];
    float* out = (float*)d_out;

    int N_ = in_sizes[0] / 128;
    int E_ = in_sizes[1] / 2;
    const int* src = ei;
    const int* dst = ei + E_;

    char* ws = (char*)d_ws;
    unsigned* bufA = (unsigned*)ws; ws += (size_t)(N_ + 1) * 64 * 4;  // bf16 table + sentinel row
    unsigned* h1b  = (unsigned*)ws; ws += (size_t)N_ * 64 * 4;        // bf16 h1 / JK
    int*   counts  = (int*)ws;    ws += (size_t)N_ * 4;
    int*   offsets = (int*)ws;    ws += (size_t)N_ * 4;
    float* dinv    = (float*)ws;  ws += (size_t)N_ * 4;
    int*   rank    = (int*)ws;    ws += (size_t)E_ * 4;
    // padded edge list (4-B src indices): sum((c+7)&~7) <= E+7N; +128 tail
    int*   el      = (int*)ws;    ws += ((size_t)E_ + 7 * (size_t)N_ + 128) * 4;
    int*   bsums   = (int*)ws;    ws += 1024 * 4;
    unsigned* W1b  = (unsigned*)ws; ws += 128 * 64 * 4;               // bf16 W^T [n][k]
    unsigned* W2b  = (unsigned*)ws; ws += 128 * 64 * 4;

    int nb = (N_ + 1023) / 1024;
    int gemmBlocks = (N_ + 63) / 64;
    int edgeBlocks = (E_ + 1023) / 1024;  // 4 edges/thread

    prep_k<<<2 + (N_ + 255) / 256, 256, 0, stream>>>(W1, W2, W1b, W2b,
                                                     counts, bufA, N_);
    count_rank_k<<<edgeBlocks, 256, 0, stream>>>(dst, counts, rank, E_);
    scan1_k<<<nb, 256, 0, stream>>>(counts, offsets, bsums, N_);
    scan2_k<<<1, 128, 0, stream>>>(bsums, nb, el, N_);
    finalize_k<<<(N_ + 255) / 256, 256, 0, stream>>>(offsets, dinv,
                                                     counts, bsums, el, N_);
    scatter_k<<<edgeBlocks, 256, 0, stream>>>(src, dst, rank, offsets, el, E_);

    // layer 1 (pre-scaled table)
    gemm_mfma_k<<<gemmBlocks, 256, 0, stream>>>(x, W1b, dinv, bufA, N_);
    agg1_k<<<(N_ + 3) / 4, 256, 0, stream>>>(bufA, el, offsets, counts, dinv,
                                             b1, gamma, beta, mean, var, h1b, N_);
    // layer 2 (bf16 A -> single-mfma gemm, pre-scaled table)
    gemm_bf16_k<<<gemmBlocks, 256, 0, stream>>>(h1b, W2b, dinv, bufA, N_);
    agg2_k<<<(N_ + 3) / 4, 256, 0, stream>>>(bufA, el, offsets, counts, dinv,
                                             b2, h1b, N_);
    // head: h1b now holds jk = max(h1, h2) in bf16; 64 nodes per block
    head_k<<<(N_ + 63) / 64, 256, 0, stream>>>(h1b, Wf, bf, out, N_);
}